// Round 3
// baseline (478.217 us; speedup 1.0000x reference)
//
#include <hip/hip_runtime.h>

// ---------- problem constants ----------
#define B_   4
#define L_   2048
#define H_   1024
#define KD   768
#define VD   1536
#define NHh  12
#define DKh  64
#define DVh  128
#define M_   (B_ * L_)   // 8192 rows
#define NC   32          // chunks per sequence (L/64)
#define NCID (B_ * NHh * NC)  // 1536

using bf16x8 = __attribute__((ext_vector_type(8))) __bf16;
using f32x4  = __attribute__((ext_vector_type(4))) float;
using ui4    = __attribute__((ext_vector_type(4))) unsigned int;
using f4v    = __attribute__((ext_vector_type(4))) float;
using u16x4  = __attribute__((ext_vector_type(4))) unsigned short;
using u16x8  = __attribute__((ext_vector_type(8))) unsigned short;

__device__ __forceinline__ float bf2f(unsigned short u) {
  unsigned int x = ((unsigned int)u) << 16;
  return __builtin_bit_cast(float, x);
}
__device__ __forceinline__ unsigned short f2bf(float f) {
  unsigned int u = __builtin_bit_cast(unsigned int, f);
  u += 0x7fffu + ((u >> 16) & 1u);
  return (unsigned short)(u >> 16);
}
__device__ __forceinline__ float sigmoidf_(float x) { return 1.f / (1.f + __expf(-x)); }

// async global->LDS DMA, 16B per lane; lds dest must be wave-uniform base (+lane*16 implicit)
__device__ __forceinline__ void async_copy16(const unsigned short* __restrict__ g,
                                             unsigned short* l) {
  __builtin_amdgcn_global_load_lds((const __attribute__((address_space(1))) unsigned int*)g,
                                   (__attribute__((address_space(3))) unsigned int*)l, 16, 0, 0);
}

// ---------- dtype detector: flag=1 if inputs are fp32, 0 if bf16 ----------
__global__ void detect_dtype(const unsigned short* __restrict__ hs, int* __restrict__ flag) {
  int tid = threadIdx.x;  // 256 threads
  int cnt = 0;
  for (int i = tid; i < 1024; i += 256) {
    int e = (hs[i] >> 7) & 0xFF;
    if (e >= 134) cnt++;
  }
  #pragma unroll
  for (int off = 32; off; off >>= 1) cnt += __shfl_xor(cnt, off);
  __shared__ int red[4];
  if ((tid & 63) == 0) red[tid >> 6] = cnt;
  __syncthreads();
  if (tid == 0) *flag = (red[0] + red[1] + red[2] + red[3] > 100) ? 1 : 0;
}

// ---------- convert hidden_states -> canonical bf16 ----------
__global__ void convert_hs4(const void* __restrict__ src, unsigned short* __restrict__ dst,
                            const int* __restrict__ flag) {
  size_t i = ((size_t)blockIdx.x * 256 + threadIdx.x) * 4;
  if (*flag) {
    f4v v = *(const f4v*)((const float*)src + i);
    u16x4 o;
    o.x = f2bf(v[0]); o.y = f2bf(v[1]); o.z = f2bf(v[2]); o.w = f2bf(v[3]);
    *(u16x4*)(dst + i) = o;
  } else {
    *(u16x4*)(dst + i) = *(const u16x4*)((const unsigned short*)src + i);
  }
}

// ---------- convert 7 small arrays -> canonical fp32 ----------
// conv weights (a=0,1,2) are additionally TRANSPOSED: in [C][4] -> out [4][C]
__global__ void convert_small(const void* s0, const void* s1, const void* s2,
                              const void* s3, const void* s4, const void* s5, const void* s6,
                              float* d0, float* d1, float* d2, float* d3, float* d4,
                              float* d5, float* d6, const int* __restrict__ flag) {
  const int sizes[7] = {KD * 4, KD * 4, VD * 4, NHh, NHh, NHh, DVh};
  int a = blockIdx.y;
  const void* s; float* d;
  switch (a) {
    case 0: s = s0; d = d0; break;  case 1: s = s1; d = d1; break;
    case 2: s = s2; d = d2; break;  case 3: s = s3; d = d3; break;
    case 4: s = s4; d = d4; break;  case 5: s = s5; d = d5; break;
    default: s = s6; d = d6; break;
  }
  int i = blockIdx.x * 256 + threadIdx.x;
  if (i >= sizes[a]) return;
  float v = (*flag) ? ((const float*)s)[i] : bf2f(((const unsigned short*)s)[i]);
  if (a < 3) {
    int C = (a == 2) ? VD : KD;
    d[(i & 3) * C + (i >> 2)] = v;   // transposed [j][c]
  } else {
    d[i] = v;
  }
}

// ---------- weight transpose+convert: in [R][C] (flag dtype) -> out bf16 [C][R] ----------
__global__ void transpose_conv(const void* __restrict__ in, unsigned short* __restrict__ out,
                               int R, int C, const int* __restrict__ flag) {
  __shared__ unsigned short tile[32][33];
  int f = *flag;
  int c0 = blockIdx.x * 32, r0 = blockIdx.y * 32;
  int tx = threadIdx.x & 31, ty = threadIdx.x >> 5;
  #pragma unroll
  for (int i = 0; i < 32; i += 8) {
    int r = r0 + ty + i, c = c0 + tx;
    unsigned short v = 0;
    if (r < R && c < C)
      v = f ? f2bf(((const float*)in)[(size_t)r * C + c])
            : ((const unsigned short*)in)[(size_t)r * C + c];
    tile[ty + i][tx] = v;
  }
  __syncthreads();
  #pragma unroll
  for (int i = 0; i < 32; i += 8) {
    int c = c0 + ty + i, r = r0 + tx;
    if (c < C && r < R) out[(size_t)c * R + r] = tile[tx][ty + i];
  }
}

// ---------- small MFMA GEMM (m97-style, 128x128): used for logits only ----------
#define BMt 128
#define BNt 128
#define BKt 64

__global__ __launch_bounds__(256, 2) void gemm_bt(
    const unsigned short* __restrict__ Ag,
    const unsigned short* __restrict__ BTg,
    void* __restrict__ Cg,
    int M, int N, int K, int f32mode, const int* __restrict__ flag) {
  __shared__ __align__(16) unsigned short As[2][BMt * BKt];
  __shared__ __align__(16) unsigned short Bs[2][BNt * BKt];
  const int tid = threadIdx.x;
  const int wave = tid >> 6, lane = tid & 63;
  const int wr = wave >> 1, wc = wave & 1;
  const int lrow = lane & 15, lq = lane >> 4;
  const int row0 = blockIdx.x * BMt;
  const int bcol0 = blockIdx.y * BNt;
  f32x4 acc[4][4] = {};
  auto stage = [&](int sb, int k0) {
    #pragma unroll
    for (int i = 0; i < 4; i++) {
      int c = i * 256 + tid;
      int r = c >> 3;
      int kk = ((c & 7) ^ (r & 7)) << 3;
      int ldsbase = (i * 256 + wave * 64) * 8;
      async_copy16(&Ag[(size_t)(row0 + r) * K + k0 + kk], &As[sb][ldsbase]);
      async_copy16(&BTg[(size_t)(bcol0 + r) * K + k0 + kk], &Bs[sb][ldsbase]);
    }
  };
  stage(0, 0);
  __syncthreads();
  int cur = 0;
  for (int k0 = 0; k0 < K; k0 += BKt) {
    if (k0 + BKt < K) stage(cur ^ 1, k0 + BKt);
    #pragma unroll
    for (int ks = 0; ks < BKt; ks += 32) {
      bf16x8 af[4], bfr[4];
      #pragma unroll
      for (int i = 0; i < 4; i++) {
        int ra = wr * 64 + i * 16 + lrow;
        int sa = ((ks >> 3) + lq) ^ (ra & 7);
        af[i]  = *(const bf16x8*)&As[cur][ra * BKt + (sa << 3)];
        int rb = wc * 64 + i * 16 + lrow;
        int sb2 = ((ks >> 3) + lq) ^ (rb & 7);
        bfr[i] = *(const bf16x8*)&Bs[cur][rb * BKt + (sb2 << 3)];
      }
      #pragma unroll
      for (int mi = 0; mi < 4; mi++)
        #pragma unroll
        for (int ni = 0; ni < 4; ni++)
          acc[mi][ni] = __builtin_amdgcn_mfma_f32_16x16x32_bf16(af[mi], bfr[ni], acc[mi][ni], 0, 0, 0);
    }
    __syncthreads();
    cur ^= 1;
  }
  bool f32 = (f32mode == 1) || (f32mode == 2 && *flag != 0);
  #pragma unroll
  for (int mi = 0; mi < 4; mi++)
    #pragma unroll
    for (int ni = 0; ni < 4; ni++)
      #pragma unroll
      for (int r = 0; r < 4; r++) {
        int rr = row0 + wr * 64 + mi * 16 + lq * 4 + r;
        int cc = bcol0 + wc * 64 + ni * 16 + lrow;
        float v = acc[mi][ni][r];
        if (f32) ((float*)Cg)[(size_t)rr * N + cc] = v;
        else     ((unsigned short*)Cg)[(size_t)rr * N + cc] = f2bf(v);
      }
}

// ---------- big MFMA GEMM: 256xBNq tile, 512 threads (8 waves 2x4), BK=64 ----------
// Deep pipeline (T3/T4): 2-tile lookahead, counted vmcnt (never 0 in main loop),
// raw s_barrier; XOR swizzle both-sides (verified conflict-free in round 2).
// Per iter: vmcnt(NLD) -> barrier -> compute(buf) -> barrier -> stage(buf, t+2).
// f32mode: 0=bf16, 1=f32, 2=flag-selected, 3=fused q|k|v|g routing (1536-col regions).
template<int BNq>
__global__ __launch_bounds__(512, 2) void gemm256(
    const unsigned short* __restrict__ Ag,
    const unsigned short* __restrict__ BTg,
    void* __restrict__ Cg,
    int M, int N, int K, int f32mode, const int* __restrict__ flag) {
  constexpr int BM = 256, BK = 64;
  constexpr int NF = BNq / 64;      // N-fragments per wave (4 or 2)
  constexpr int NLD = 4 + NF;       // global_load_lds per thread per K-tile
  __shared__ __align__(16) unsigned short As[2][BM * BK];
  __shared__ __align__(16) unsigned short Bs[2][BNq * BK];
  const int tid = threadIdx.x;
  const int wave = tid >> 6, lane = tid & 63;
  const int wr = wave >> 2, wc = wave & 3;     // 2 x 4 wave grid
  const int lrow = lane & 15, lq = lane >> 4;
  const int row0 = blockIdx.x * BM;
  const int bcol0 = blockIdx.y * BNq;
  unsigned short* Cb = (unsigned short*)Cg;
  int col0 = bcol0, Nst = N;
  if (f32mode == 3) {
    int region = bcol0 / 1536;
    Cb += (size_t)region * (size_t)M_ * 1536;
    col0 = bcol0 - region * 1536;
    Nst = 1536;
  }
  f32x4 acc[8][NF] = {};
  auto stage = [&](int sb, int k0) {
    #pragma unroll
    for (int i = 0; i < 4; i++) {
      int c = i * 512 + tid;
      int r = c >> 3;
      int kk = ((c & 7) ^ (r & 7)) << 3;   // pre-swizzled source slot
      async_copy16(&Ag[(size_t)(row0 + r) * K + k0 + kk],
                   &As[sb][(i * 512 + wave * 64) * 8]);
    }
    #pragma unroll
    for (int i = 0; i < NF; i++) {
      int c = i * 512 + tid;
      int r = c >> 3;
      int kk = ((c & 7) ^ (r & 7)) << 3;
      async_copy16(&BTg[(size_t)(bcol0 + r) * K + k0 + kk],
                   &Bs[sb][(i * 512 + wave * 64) * 8]);
    }
  };
  const int NT = K / BK;
  stage(0, 0);
  stage(1, BK);
  int cur = 0;
  for (int t = 0; t < NT; t++) {
    // Drain only THIS tile's loads (own-wave); tile t+1's stay in flight.
    if (t + 1 < NT) asm volatile("s_waitcnt vmcnt(%0)" :: "i"(NLD) : "memory");
    else            asm volatile("s_waitcnt vmcnt(0)" ::: "memory");
    __builtin_amdgcn_s_barrier();   // all waves' tile-t loads are in LDS
    #pragma unroll
    for (int ks = 0; ks < 2; ks++) {
      bf16x8 af[8], bfv[NF];
      #pragma unroll
      for (int i = 0; i < 8; i++) {
        int ra = wr * 128 + i * 16 + lrow;
        int sa = ((ks << 2) + lq) ^ (ra & 7);
        af[i] = *(const bf16x8*)&As[cur][ra * BK + (sa << 3)];
      }
      #pragma unroll
      for (int i = 0; i < NF; i++) {
        int rb = wc * (BNq / 4) + i * 16 + lrow;
        int sb2 = ((ks << 2) + lq) ^ (rb & 7);
        bfv[i] = *(const bf16x8*)&Bs[cur][rb * BK + (sb2 << 3)];
      }
      __builtin_amdgcn_s_setprio(1);
      #pragma unroll
      for (int mi = 0; mi < 8; mi++)
        #pragma unroll
        for (int ni = 0; ni < NF; ni++)
          acc[mi][ni] = __builtin_amdgcn_mfma_f32_16x16x32_bf16(af[mi], bfv[ni], acc[mi][ni], 0, 0, 0);
      __builtin_amdgcn_s_setprio(0);
    }
    __builtin_amdgcn_s_barrier();   // all waves done reading buffer cur
    if (t + 2 < NT) stage(cur, (t + 2) * BK);   // safe: buffer released by barrier
    cur ^= 1;
  }
  bool f32 = (f32mode == 1) || (f32mode == 2 && *flag != 0);
  #pragma unroll
  for (int mi = 0; mi < 8; mi++)
    #pragma unroll
    for (int ni = 0; ni < NF; ni++)
      #pragma unroll
      for (int r = 0; r < 4; r++) {
        int rr = row0 + wr * 128 + mi * 16 + lq * 4 + r;
        int cc = col0 + wc * (BNq / 4) + ni * 16 + lrow;
        float v = acc[mi][ni][r];
        if (f32) ((float*)Cg)[(size_t)rr * N + cc] = v;
        else     Cb[(size_t)rr * Nst + cc] = f2bf(v);
      }
}

// ---------- gk/beta from fp32 logits [M][128] (cols 0..11 gk, 12..23 beta) ----------
__global__ void gkbeta_kernel(const float* __restrict__ logits,
                              const float* __restrict__ bb,
                              const float* __restrict__ A_log,
                              const float* __restrict__ dt_bias,
                              float* __restrict__ gkb, float* __restrict__ betab) {
  int idx = blockIdx.x * 256 + threadIdx.x;   // m*24 + j
  int m = idx / 24, j = idx - m * 24;
  float x = logits[(size_t)m * 128 + j];
  if (j < 12) {
    float t = x + dt_bias[j];
    float sp = (t > 20.f) ? t : log1pf(__expf(t));
    gkb[m * NHh + j] = -__expf(A_log[j]) * sp;
  } else {
    betab[m * NHh + (j - 12)] = sigmoidf_(x + bb[j - 12]);
  }
}

// ---------- causal dwconv(K=4) + silu + per-head l2norm (q/k, strided src) ----------
__global__ __launch_bounds__(192) void conv_qk_kernel(
    const unsigned short* __restrict__ raw, int rstride,
    const float* __restrict__ w,
    unsigned short* __restrict__ outp) {
  int tid = threadIdx.x;
  int rib = tid / 96, within = tid - rib * 96;   // row-in-block, 0..95
  int bl = blockIdx.x * 2 + rib;
  int c = within * 8;                             // channel base 0..760
  int l = bl & (L_ - 1);
  float acc[8] = {};
  #pragma unroll
  for (int j = 0; j < 4; j++) {
    int ll = l - 3 + j;
    if (ll >= 0) {
      u16x8 v = *(const u16x8*)&raw[(size_t)(bl - 3 + j) * rstride + c];
      f4v w0 = *(const f4v*)&w[j * KD + c];
      f4v w1 = *(const f4v*)&w[j * KD + c + 4];
      #pragma unroll
      for (int e = 0; e < 4; e++) acc[e] += bf2f(v[e]) * w0[e];
      #pragma unroll
      for (int e = 0; e < 4; e++) acc[4 + e] += bf2f(v[4 + e]) * w1[e];
    }
  }
  float x[8], ss = 0.f;
  #pragma unroll
  for (int e = 0; e < 8; e++) {
    float a = acc[e];
    x[e] = a * sigmoidf_(a);
    ss += x[e] * x[e];
  }
  #pragma unroll
  for (int off = 1; off <= 4; off <<= 1) ss += __shfl_xor(ss, off);
  float inv = 1.f / fmaxf(sqrtf(ss), 1e-12f);
  u16x8 o;
  #pragma unroll
  for (int e = 0; e < 8; e++) o[e] = f2bf(x[e] * inv);
  *(u16x8*)&outp[(size_t)bl * KD + c] = o;
}

// ---------- causal dwconv(K=4) + silu for v ----------
__global__ void conv_v_kernel(const unsigned short* __restrict__ raw,
                              const float* __restrict__ w,
                              unsigned short* __restrict__ outp) {
  int idx = blockIdx.x * 256 + threadIdx.x;   // M_ * 192 tasks
  int bl = idx / 192;
  int c = (idx - bl * 192) * 8;
  int l = bl & (L_ - 1);
  float acc[8] = {};
  #pragma unroll
  for (int j = 0; j < 4; j++) {
    int ll = l - 3 + j;
    if (ll >= 0) {
      u16x8 v = *(const u16x8*)&raw[(size_t)(bl - 3 + j) * VD + c];
      f4v w0 = *(const f4v*)&w[j * VD + c];
      f4v w1 = *(const f4v*)&w[j * VD + c + 4];
      #pragma unroll
      for (int e = 0; e < 4; e++) acc[e] += bf2f(v[e]) * w0[e];
      #pragma unroll
      for (int e = 0; e < 4; e++) acc[4 + e] += bf2f(v[4 + e]) * w1[e];
    }
  }
  u16x8 o;
  #pragma unroll
  for (int e = 0; e < 8; e++) {
    float a = acc[e];
    o[e] = f2bf(a * sigmoidf_(a));
  }
  *(u16x8*)&outp[(size_t)bl * VD + c] = o;
}

// ================= CHUNKED GATED DELTA RULE =================
// ---------- Phase 1: per-chunk precompute (parallel, 1536 blocks) ----------
__global__ __launch_bounds__(256) void phase1_kernel(
    const unsigned short* __restrict__ kb, const unsigned short* __restrict__ vb,
    const float* __restrict__ gkb, const float* __restrict__ betab,
    unsigned short* __restrict__ U0g, unsigned short* __restrict__ Wmg,
    float* __restrict__ Gamg) {
  int cid = blockIdx.x;
  int c = cid & (NC - 1), bh = cid >> 5;
  int h = bh % NHh, b = bh / NHh;
  int bl0 = b * L_ + (c << 6);
  __shared__ __align__(16) unsigned short K_lds[64][72];
  __shared__ __align__(16) unsigned short Ab[64][72];
  __shared__ __align__(16) unsigned short Tb[64][72];
  __shared__ __align__(16) unsigned short TbT[64][72];
  __shared__ __align__(16) unsigned short Qt[64][40];
  __shared__ __align__(16) unsigned short Mpad[16][40];
  __shared__ __align__(16) unsigned short RHSt[192][72];
  __shared__ float G_lds[64], beta_lds[64], besc_lds[64];
  int tid = threadIdx.x;
  int wave = tid >> 6, lane = tid & 63, lq = lane >> 4, lrow = lane & 15;
  {
    u16x4 z = {};
    unsigned short* tb = &Tb[0][0];  unsigned short* tt = &TbT[0][0];
    for (int i = tid * 4; i < 64 * 72; i += 1024) {
      *(u16x4*)&tb[i] = z;  *(u16x4*)&tt[i] = z;
    }
    unsigned short* qt = &Qt[0][0];
    for (int i = tid * 4; i < 64 * 40; i += 1024) *(u16x4*)&qt[i] = z;
    if (tid < 160) *(u16x4*)&(&Mpad[0][0])[tid * 4] = z;
  }
  {
    int j = tid >> 2, d0 = (tid & 3) << 4;
    const ui4* src = (const ui4*)&kb[(size_t)(bl0 + j) * KD + h * 64 + d0];
    *(ui4*)&K_lds[j][d0]     = src[0];
    *(ui4*)&K_lds[j][d0 + 8] = src[1];
  }
  if (tid < 64) {
    float g  = gkb[(size_t)(bl0 + tid) * NHh + h];
    float bt = betab[(size_t)(bl0 + tid) * NHh + h];
    #pragma unroll
    for (int off = 1; off < 64; off <<= 1) {
      int src = lane - off;
      float y = __shfl(g, src < 0 ? 0 : src);
      if (lane >= off) g += y;
    }
    G_lds[tid]    = g;
    beta_lds[tid] = bt;
    besc_lds[tid] = bt * __expf(g);
    Gamg[(size_t)cid * 64 + tid] = g;
  }
  __syncthreads();
  #pragma unroll
  for (int mt = 0; mt < 4; mt++) {
    f32x4 acc = {};
    #pragma unroll
    for (int ks = 0; ks < 2; ks++) {
      bf16x8 a  = *(const bf16x8*)&K_lds[wave * 16 + lrow][ks * 32 + lq * 8];
      bf16x8 b2 = *(const bf16x8*)&K_lds[mt * 16 + lrow][ks * 32 + lq * 8];
      acc = __builtin_amdgcn_mfma_f32_16x16x32_bf16(a, b2, acc, 0, 0, 0);
    }
    #pragma unroll
    for (int r = 0; r < 4; r++) {
      int j = wave * 16 + lq * 4 + r, m = mt * 16 + lrow;
      Ab[j][m] = (m < j) ? f2bf(beta_lds[j] * __expf(G_lds[j] - G_lds[m]) * acc[r])
                         : (unsigned short)0;
    }
  }
  __syncthreads();
  if (wave == 0) {
    int blk = lq, cc = lrow, base = blk * 16;
    float t[16];
    t[0] = (cc == 0) ? 1.f : 0.f;
    #pragma unroll
    for (int j = 1; j < 16; j++) {
      float s = 0.f;
      #pragma unroll
      for (int m = 0; m < j; m++)
        s += bf2f(Ab[base + j][base + m]) * t[m];
      t[j] = ((cc == j) ? 1.f : 0.f) - s;
    }
    #pragma unroll
    for (int j = 0; j < 16; j++) {
      unsigned short bv = f2bf(t[j]);
      Tb[base + j][base + cc]  = bv;
      TbT[base + cc][base + j] = bv;
    }
  } else {
    int r = tid - 64;   // 0..191
    if (r < 128) {
      const unsigned short* vp = &vb[(size_t)bl0 * VD + h * 128 + r];
      for (int j = 0; j < 64; j++)
        RHSt[r][j] = f2bf(beta_lds[j] * bf2f(vp[(size_t)j * VD]));
    } else {
      int d = r - 128;
      for (int j = 0; j < 64; j++)
        RHSt[r][j] = f2bf(besc_lds[j] * bf2f(K_lds[j][d]));
    }
  }
  __syncthreads();
  #pragma unroll
  for (int lvl = 1; lvl < 4; lvl++) {
    {
      int m = tid >> 4, k = tid & 15;
      Ab[lvl * 16 + m][lvl * 16 + k] = 0;
      Mpad[m][k] = Tb[lvl * 16 + m][lvl * 16 + k];
    }
    __syncthreads();
    f32x4 accP = {};
    #pragma unroll
    for (int ks2 = 0; ks2 < 2; ks2++) {
      bf16x8 a  = *(const bf16x8*)&Ab[lvl * 16 + lrow][ks2 * 32 + lq * 8];
      bf16x8 b2 = *(const bf16x8*)&TbT[wave * 16 + lrow][ks2 * 32 + lq * 8];
      accP = __builtin_amdgcn_mfma_f32_16x16x32_bf16(a, b2, accP, 0, 0, 0);
    }
    {
      int col = wave * 16 + lrow;
      u16x4 qp;
      #pragma unroll
      for (int r = 0; r < 4; r++) {
        int krow = lq * 4 + r;
        float e = (col == lvl * 16 + krow) ? 1.f : 0.f;
        ((unsigned short*)&qp)[r] = f2bf(e - accP[r]);
      }
      *(u16x4*)&Qt[col][lq * 4] = qp;
    }
    __syncthreads();
    {
      bf16x8 am = *(const bf16x8*)&Mpad[lrow][lq * 8];
      bf16x8 bq = *(const bf16x8*)&Qt[wave * 16 + lrow][lq * 8];
      f32x4 accR = {};
      accR = __builtin_amdgcn_mfma_f32_16x16x32_bf16(am, bq, accR, 0, 0, 0);
      #pragma unroll
      for (int r = 0; r < 4; r++) {
        int row = lvl * 16 + lq * 4 + r, col = wave * 16 + lrow;
        unsigned short bv = f2bf(accR[r]);
        Tb[row][col]  = bv;
        TbT[col][row] = bv;
      }
    }
    __syncthreads();
  }
  bf16x8 af0 = *(const bf16x8*)&Tb[wave * 16 + lrow][lq * 8];
  bf16x8 af1 = *(const bf16x8*)&Tb[wave * 16 + lrow][32 + lq * 8];
  #pragma unroll
  for (int nt = 0; nt < 12; nt++) {
    f32x4 acc = {};
    bf16x8 b0 = *(const bf16x8*)&RHSt[nt * 16 + lrow][lq * 8];
    bf16x8 b1 = *(const bf16x8*)&RHSt[nt * 16 + lrow][32 + lq * 8];
    acc = __builtin_amdgcn_mfma_f32_16x16x32_bf16(af0, b0, acc, 0, 0, 0);
    acc = __builtin_amdgcn_mfma_f32_16x16x32_bf16(af1, b1, acc, 0, 0, 0);
    #pragma unroll
    for (int r = 0; r < 4; r++) {
      int i = wave * 16 + lq * 4 + r;
      int col = nt * 16 + lrow;
      if (nt < 8) U0g[(size_t)cid * 8192 + i * 128 + col] = f2bf(acc[r]);
      else        Wmg[(size_t)cid * 4096 + i * 64 + (col - 128)] = f2bf(acc[r]);
    }
  }
}

// ---------- Phase 2: inter-chunk state recurrence, v-split (192 blocks) ----------
__global__ __launch_bounds__(256) void phase2_kernel(
    const unsigned short* __restrict__ kb,
    const unsigned short* __restrict__ U0g, const unsigned short* __restrict__ Wmg,
    const float* __restrict__ Gamg, unsigned short* __restrict__ P0g) {
  int blk = blockIdx.x;              // bh*4 + vc
  int vc = blk & 3, bh = blk >> 2;
  int h = bh % NHh, b = bh / NHh;
  __shared__ __align__(16) unsigned short P_bf[32][72];    // S0 slice [v][d]
  __shared__ __align__(16) unsigned short Wm_lds[64][72];  // [j][d]
  __shared__ __align__(16) unsigned short Ktmp[64][72];    // [j][d]
  __shared__ __align__(16) unsigned short KpT_lds[64][72]; // [d][j]
  __shared__ __align__(16) unsigned short U0_lds[64][40];  // [j][v32]
  __shared__ __align__(16) unsigned short UT_lds[32][72];  // [v][j]
  __shared__ float G2[64];
  int tid = threadIdx.x;
  int wave = tid >> 6, lane = tid & 63, lq = lane >> 4, lrow = lane & 15;
  int vt = wave & 1, dbase = (wave >> 1) * 2;
  f32x4 P[2] = {};
  int pj = tid >> 2, px = (tid & 3) << 4;   // Wm/K: 32B per thread
  int pv = (tid & 3) << 3;                  // U0: 16B per thread (8 shorts)
  ui4 pf_wm0, pf_wm1, pf_k0, pf_k1, pf_u0;
  float pf_g = 0.f;
  {
    size_t cid0 = (size_t)bh * NC;
    int bl0 = b * L_;
    pf_wm0 = *(const ui4*)&Wmg[cid0 * 4096 + pj * 64 + px];
    pf_wm1 = *(const ui4*)&Wmg[cid0 * 4096 + pj * 64 + px + 8];
    pf_k0  = *(const ui4*)&kb[(size_t)(bl0 + pj) * KD + h * 64 + px];
    pf_k1  = *(const ui4*)&kb[(size_t)(bl0 + pj) * KD + h * 64 + px + 8];
    pf_u0  = *(const ui4*)&U0g[cid0 * 8192 + pj * 128 + vc * 32 + pv];
    if (tid < 64) pf_g = Gamg[cid0 * 64 + tid];
  }
  for (int c = 0; c < NC; c++) {
    size_t cid = (size_t)bh * NC + c;
    #pragma unroll
    for (int di = 0; di < 2; di++)
      #pragma unroll
      for (int r = 0; r < 4; r++)
        P_bf[vt * 16 + lq * 4 + r][(dbase + di) * 16 + lrow] = f2bf(P[di][r]);
    *(ui4*)&Wm_lds[pj][px]     = pf_wm0;
    *(ui4*)&Wm_lds[pj][px + 8] = pf_wm1;
    *(ui4*)&Ktmp[pj][px]       = pf_k0;
    *(ui4*)&Ktmp[pj][px + 8]   = pf_k1;
    *(ui4*)&U0_lds[pj][pv]     = pf_u0;
    if (tid < 64) G2[tid] = pf_g;
    __syncthreads();
    float gend = __expf(G2[63]);
    {
      int v = tid >> 3, d8 = (tid & 7) << 3;
      *(ui4*)&P0g[cid * 8192 + (size_t)(vc * 32 + v) * 64 + d8] = *(const ui4*)&P_bf[v][d8];
    }
    if (c + 1 < NC) {
      size_t cid1 = cid + 1;
      int bl1 = b * L_ + ((c + 1) << 6);
      pf_wm0 = *(const ui4*)&Wmg[cid1 * 4096 + pj * 64 + px];
      pf_wm1 = *(const ui4*)&Wmg[cid1 * 4096 + pj * 64 + px + 8];
      pf_k0  = *(const ui4*)&kb[(size_t)(bl1 + pj) * KD + h * 64 + px];
      pf_k1  = *(const ui4*)&kb[(size_t)(bl1 + pj) * KD + h * 64 + px + 8];
      pf_u0  = *(const ui4*)&U0g[cid1 * 8192 + pj * 128 + vc * 32 + pv];
      if (tid < 64) pf_g = Gamg[cid1 * 64 + tid];
    }
    {
      int d = tid & 63, j0 = (tid >> 6) << 4;
      float Ge = G2[63];
      #pragma unroll
      for (int i = 0; i < 16; i++) {
        int j = j0 + i;
        KpT_lds[d][j] = f2bf(__expf(Ge - G2[j]) * bf2f(Ktmp[j][d]));
      }
    }
    #pragma unroll
    for (int vt2 = 0; vt2 < 2; vt2++) {
      f32x4 acc = {};
      #pragma unroll
      for (int ks2 = 0; ks2 < 2; ks2++) {
        bf16x8 a  = *(const bf16x8*)&Wm_lds[wave * 16 + lrow][ks2 * 32 + lq * 8];
        bf16x8 b2 = *(const bf16x8*)&P_bf[vt2 * 16 + lrow][ks2 * 32 + lq * 8];
        acc = __builtin_amdgcn_mfma_f32_16x16x32_bf16(a, b2, acc, 0, 0, 0);
      }
      u16x4 p;
      #pragma unroll
      for (int r = 0; r < 4; r++) {
        int j = wave * 16 + lq * 4 + r;
        ((unsigned short*)&p)[r] = f2bf(bf2f(U0_lds[j][vt2 * 16 + lrow]) - acc[r]);
      }
      *(u16x4*)&UT_lds[vt2 * 16 + lrow][wave * 16 + lq * 4] = p;
    }
    __syncthreads();
    #pragma unroll
    for (int di = 0; di < 2; di++) {
      f32x4 acc = P[di];
      #pragma unroll
      for (int r = 0; r < 4; r++) acc[r] *= gend;
      #pragma unroll
      for (int ks2 = 0; ks2 < 2; ks2++) {
        bf16x8 a  = *(const bf16x8*)&UT_lds[vt * 16 + lrow][ks2 * 32 + lq * 8];
        bf16x8 b2 = *(const bf16x8*)&KpT_lds[(dbase + di) * 16 + lrow][ks2 * 32 + lq * 8];
        acc = __builtin_amdgcn_mfma_f32_16x16x32_bf16(a, b2, acc, 0, 0, 0);
      }
      P[di] = acc;
    }
  }
}

// ---------- Phase 3: per-chunk output (parallel, 1536 blocks) ----------
__global__ __launch_bounds__(256) void phase3_kernel(
    const unsigned short* __restrict__ qb, const unsigned short* __restrict__ kb,
    const unsigned short* __restrict__ U0g, const unsigned short* __restrict__ Wmg,
    const unsigned short* __restrict__ P0g, const float* __restrict__ Gamg,
    unsigned short* __restrict__ o_raw) {
  int cid = blockIdx.x;
  int c = cid & (NC - 1), bh = cid >> 5;
  int h = bh % NHh, b = bh / NHh;
  int bl0 = b * L_ + (c << 6);
  __shared__ __align__(16) unsigned short Q_lds[64][72];
  __shared__ __align__(16) unsigned short K_lds[64][72];
  __shared__ __align__(16) unsigned short WM_lds[64][72];
  __shared__ __align__(16) unsigned short P0_lds[128][72];
  __shared__ __align__(16) unsigned short U0_lds[64][128];
  __shared__ __align__(16) unsigned short UT_lds[128][72];
  __shared__ float G_lds[64];
  int tid = threadIdx.x;
  int wave = tid >> 6, lane = tid & 63, lq = lane >> 4, lrow = lane & 15;
  {
    int j = tid >> 2, d0 = (tid & 3) << 4;
    const ui4* qs = (const ui4*)&qb[(size_t)(bl0 + j) * KD + h * 64 + d0];
    *(ui4*)&Q_lds[j][d0] = qs[0];  *(ui4*)&Q_lds[j][d0 + 8] = qs[1];
    const ui4* ks = (const ui4*)&kb[(size_t)(bl0 + j) * KD + h * 64 + d0];
    *(ui4*)&K_lds[j][d0] = ks[0];  *(ui4*)&K_lds[j][d0 + 8] = ks[1];
    const ui4* ws = (const ui4*)&Wmg[(size_t)cid * 4096 + j * 64 + d0];
    *(ui4*)&WM_lds[j][d0] = ws[0]; *(ui4*)&WM_lds[j][d0 + 8] = ws[1];
    int v = tid >> 1, e0 = (tid & 1) << 5;
    const ui4* ps = (const ui4*)&P0g[(size_t)cid * 8192 + v * 64 + e0];
    *(ui4*)&P0_lds[v][e0]      = ps[0]; *(ui4*)&P0_lds[v][e0 + 8]  = ps[1];
    *(ui4*)&P0_lds[v][e0 + 16] = ps[2]; *(ui4*)&P0_lds[v][e0 + 24] = ps[3];
    int e1 = tid * 32;
    const ui4* us = (const ui4*)&U0g[(size_t)cid * 8192 + e1];
    ui4* ud = (ui4*)&U0_lds[0][e1];
    ud[0] = us[0]; ud[1] = us[1]; ud[2] = us[2]; ud[3] = us[3];
    if (tid < 64) G_lds[tid] = Gamg[(size_t)cid * 64 + tid];
  }
  __syncthreads();
  #pragma unroll
  for (int nt = 0; nt < 8; nt++) {
    f32x4 acc = {};
    #pragma unroll
    for (int ks2 = 0; ks2 < 2; ks2++) {
      bf16x8 a  = *(const bf16x8*)&WM_lds[wave * 16 + lrow][ks2 * 32 + lq * 8];
      bf16x8 b2 = *(const bf16x8*)&P0_lds[nt * 16 + lrow][ks2 * 32 + lq * 8];
      acc = __builtin_amdgcn_mfma_f32_16x16x32_bf16(a, b2, acc, 0, 0, 0);
    }
    u16x4 p;
    #pragma unroll
    for (int r = 0; r < 4; r++) {
      int j = wave * 16 + lq * 4 + r;
      ((unsigned short*)&p)[r] = f2bf(bf2f(U0_lds[j][nt * 16 + lrow]) - acc[r]);
    }
    *(u16x4*)&UT_lds[nt * 16 + lrow][wave * 16 + lq * 4] = p;
  }
  __syncthreads();
  #pragma unroll
  for (int mt = 0; mt < 4; mt++) {
    f32x4 acc = {};
    #pragma unroll
    for (int ks2 = 0; ks2 < 2; ks2++) {
      bf16x8 a  = *(const bf16x8*)&Q_lds[wave * 16 + lrow][ks2 * 32 + lq * 8];
      bf16x8 b2 = *(const bf16x8*)&K_lds[mt * 16 + lrow][ks2 * 32 + lq * 8];
      acc = __builtin_amdgcn_mfma_f32_16x16x32_bf16(a, b2, acc, 0, 0, 0);
    }
    #pragma unroll
    for (int r = 0; r < 4; r++) {
      int i = wave * 16 + lq * 4 + r, j = mt * 16 + lrow;
      WM_lds[i][j] = (j <= i) ? f2bf(__expf(G_lds[i] - G_lds[j]) * acc[r]) : (unsigned short)0;
    }
  }
  __syncthreads();
  #pragma unroll
  for (int nt = 0; nt < 8; nt++) {
    f32x4 accO = {}, accS = {};
    #pragma unroll
    for (int ks2 = 0; ks2 < 2; ks2++) {
      bf16x8 aM = *(const bf16x8*)&WM_lds[wave * 16 + lrow][ks2 * 32 + lq * 8];
      bf16x8 bU = *(const bf16x8*)&UT_lds[nt * 16 + lrow][ks2 * 32 + lq * 8];
      accO = __builtin_amdgcn_mfma_f32_16x16x32_bf16(aM, bU, accO, 0, 0, 0);
      bf16x8 aQ = *(const bf16x8*)&Q_lds[wave * 16 + lrow][ks2 * 32 + lq * 8];
      bf16x8 bP = *(const bf16x8*)&P0_lds[nt * 16 + lrow][ks2 * 32 + lq * 8];
      accS = __builtin_amdgcn_mfma_f32_16x16x32_bf16(aQ, bP, accS, 0, 0, 0);
    }
    #pragma unroll
    for (int r = 0; r < 4; r++) {
      int i = wave * 16 + lq * 4 + r;
      float o = accO[r] + __expf(G_lds[i]) * accS[r];
      o_raw[(size_t)(bl0 + i) * VD + h * 128 + nt * 16 + lrow] = f2bf(o);
    }
  }
}

// ---------- rmsnorm + gnorm_w * silu(g), in-place on o_raw ----------
__global__ void norm_gate_kernel(unsigned short* __restrict__ o_raw,
                                 const unsigned short* __restrict__ g,
                                 const float* __restrict__ gnw) {
  int tid = threadIdx.x;
  int r = blockIdx.x * 16 + (tid >> 4);
  int v = (tid & 15) * 8;
  u16x8 xo = *(const u16x8*)&o_raw[(size_t)r * DVh + v];
  u16x8 xg = *(const u16x8*)&g[(size_t)r * DVh + v];
  float x[8], ss = 0.f;
  #pragma unroll
  for (int e = 0; e < 8; e++) {
    x[e] = bf2f(xo[e]);
    ss += x[e] * x[e];
  }
  #pragma unroll
  for (int off = 1; off <= 8; off <<= 1) ss += __shfl_xor(ss, off);
  float inv = rsqrtf(ss * (1.f / (float)DVh) + 1e-5f);
  f4v w0 = *(const f4v*)&gnw[v];
  f4v w1 = *(const f4v*)&gnw[v + 4];
  u16x8 o;
  #pragma unroll
  for (int e = 0; e < 8; e++) {
    float gv = bf2f(xg[e]);
    float wv = (e < 4) ? w0[e] : w1[e - 4];
    o[e] = f2bf(x[e] * inv * wv * (gv * sigmoidf_(gv)));
  }
  *(u16x8*)&o_raw[(size_t)r * DVh + v] = o;
}

// ---------- host launch ----------
extern "C" void kernel_launch(void* const* d_in, const int* in_sizes, int n_in,
                              void* d_out, int out_size, void* d_ws, size_t ws_size,
                              hipStream_t stream) {
  const void* hs      = d_in[0];
  const void* Wq      = d_in[1];
  const void* Wk      = d_in[2];
  const void* Wv      = d_in[3];
  const void* Wg      = d_in[4];
  const void* Wgk     = d_in[5];
  const void* Wb      = d_in[6];
  const void* bb      = d_in[7];
  const void* cq      = d_in[8];
  const void* ck      = d_in[9];
  const void* cv      = d_in[10];
  const void* A_log   = d_in[11];
  const void* gnorm_w = d_in[12];
  const void* Wo      = d_in[13];
  const void* dt_bias = d_in[14];

  char* wsB = (char*)d_ws;
  size_t off = 0;
  auto walloc = [&](size_t bytes) -> char* {
    char* p = wsB + off;
    off += (bytes + 1023) & ~(size_t)1023;
    return p;
  };
  int* flag = (int*)walloc(1024);
  // NOTE: WqT..WgT must stay contiguous (fused BT of [4608][1024]); all sizes
  // are multiples of 1024 so walloc adds no padding between them.
  unsigned short* WqT   = (unsigned short*)walloc((size_t)KD * H_ * 2);
  unsigned short* WkT   = (unsigned short*)walloc((size_t)KD * H_ * 2);
  unsigned short* WvT   = (unsigned short*)walloc((size_t)VD * H_ * 2);
  unsigned short* WgT   = (unsigned short*)walloc((size_t)VD * H_ * 2);
  unsigned short* WgkbT = (unsigned short*)walloc((size_t)128 * H_ * 2);
  unsigned short* WoT   = (unsigned short*)walloc((size_t)H_ * VD * 2);
  float* cqf   = (float*)walloc((size_t)KD * 4 * 4);
  float* ckf   = (float*)walloc((size_t)KD * 4 * 4);
  float* cvf   = (float*)walloc((size_t)VD * 4 * 4);
  float* bbf   = (float*)walloc(NHh * 4);
  float* A_logf= (float*)walloc(NHh * 4);
  float* dtf   = (float*)walloc(NHh * 4);
  float* gnwf  = (float*)walloc(DVh * 4);
  float* gkb   = (float*)walloc((size_t)M_ * NHh * 4);
  float* betab = (float*)walloc((size_t)M_ * NHh * 4);
  float* Gamg  = (float*)walloc((size_t)NCID * 64 * 4);
  unsigned short* c_hs  = (unsigned short*)walloc((size_t)M_ * H_ * 2);
  // qkraw/vraw/gbuf must stay contiguous (fused GEMM C routing).
  unsigned short* qkraw = (unsigned short*)walloc((size_t)M_ * 1536 * 2);
  unsigned short* vraw  = (unsigned short*)walloc((size_t)M_ * VD * 2);
  unsigned short* gbuf  = (unsigned short*)walloc((size_t)M_ * VD * 2);
  unsigned short* qb    = (unsigned short*)walloc((size_t)M_ * KD * 2);
  unsigned short* kb    = (unsigned short*)walloc((size_t)M_ * KD * 2);
  unsigned short* vb    = (unsigned short*)walloc((size_t)M_ * VD * 2);
  // overlays (safe by launch order):
  float*          logits32 = (float*)vraw;   // consumed by gkbeta BEFORE fused GEMM
  unsigned short* Wmg   = c_hs;
  unsigned short* U0g   = qkraw;
  unsigned short* o_raw = vraw;
  unsigned short* P0g   = vb;

  // 0. dtype detection + canonicalization
  detect_dtype<<<1, 256, 0, stream>>>((const unsigned short*)hs, flag);
  convert_small<<<dim3(24, 7), 256, 0, stream>>>(cq, ck, cv, bb, A_log, dt_bias, gnorm_w,
                                                 cqf, ckf, cvf, bbf, A_logf, dtf, gnwf, flag);
  transpose_conv<<<dim3(KD / 32, H_ / 32), 256, 0, stream>>>(Wq, WqT, H_, KD, flag);
  transpose_conv<<<dim3(KD / 32, H_ / 32), 256, 0, stream>>>(Wk, WkT, H_, KD, flag);
  transpose_conv<<<dim3(VD / 32, H_ / 32), 256, 0, stream>>>(Wv, WvT, H_, VD, flag);
  transpose_conv<<<dim3(VD / 32, H_ / 32), 256, 0, stream>>>(Wg, WgT, H_, VD, flag);
  transpose_conv<<<dim3(1, H_ / 32), 256, 0, stream>>>(Wgk, WgkbT, H_, NHh, flag);
  transpose_conv<<<dim3(1, H_ / 32), 256, 0, stream>>>(Wb, WgkbT + 12 * H_, H_, NHh, flag);
  transpose_conv<<<dim3(H_ / 32, VD / 32), 256, 0, stream>>>(Wo, WoT, VD, H_, flag);
  convert_hs4<<<(M_ * H_) / 1024, 256, 0, stream>>>(hs, c_hs, flag);

  // 1a. gk/beta logits first (logits32 overlays vraw; consume before fused GEMM)
  gemm_bt<<<dim3(M_ / 128, 1), 256, 0, stream>>>(c_hs, WgkbT, logits32, M_, 128, H_, 1, flag);
  gkbeta_kernel<<<(M_ * 24) / 256, 256, 0, stream>>>(logits32, bbf, A_logf, dtf, gkb, betab);
  // 1b. fused q|k|v|g projection: BT = [WqT;WkT;WvT;WgT] = [4608][1024],
  //     C routed per 256-col tile into qkraw / vraw / gbuf (mode 3)
  gemm256<256><<<dim3(M_ / 256, 4608 / 256), 512, 0, stream>>>(c_hs, WqT, qkraw, M_, 4608, H_, 3, flag);

  // 2. conv + silu (+ l2norm for q/k) — vectorized 16B/lane
  conv_qk_kernel<<<M_ / 2, 192, 0, stream>>>(qkraw, 1536, cqf, qb);
  conv_qk_kernel<<<M_ / 2, 192, 0, stream>>>(qkraw + KD, 1536, ckf, kb);
  conv_v_kernel<<<(M_ * 192) / 256, 256, 0, stream>>>(vraw, cvf, vb);

  // 3. chunked gated delta rule
  phase1_kernel<<<NCID, 256, 0, stream>>>(kb, vb, gkb, betab, U0g, Wmg, Gamg);
  phase2_kernel<<<B_ * NHh * 4, 256, 0, stream>>>(kb, U0g, Wmg, Gamg, P0g);
  phase3_kernel<<<NCID, 256, 0, stream>>>(qb, kb, U0g, Wmg, P0g, Gamg, o_raw);

  // 4. rmsnorm + swish gate (in-place on o_raw) — vectorized
  norm_gate_kernel<<<(M_ * NHh) / 16, 256, 0, stream>>>(o_raw, gbuf, gnwf);

  // 5. output projection: 256x128 tile -> grid 32x8 = 256 blocks (1/CU)
  gemm256<128><<<dim3(M_ / 256, H_ / 128), 512, 0, stream>>>(o_raw, WoT, d_out, M_, H_, VD, 2, flag);
}

// Round 4
// 470.534 us; speedup vs baseline: 1.0163x; 1.0163x over previous
//
#include <hip/hip_runtime.h>

// ---------- problem constants ----------
#define B_   4
#define L_   2048
#define H_   1024
#define KD   768
#define VD   1536
#define NHh  12
#define DKh  64
#define DVh  128
#define M_   (B_ * L_)   // 8192 rows
#define NC   32          // chunks per sequence (L/64)
#define NCID (B_ * NHh * NC)  // 1536

using bf16x8 = __attribute__((ext_vector_type(8))) __bf16;
using f32x4  = __attribute__((ext_vector_type(4))) float;
using ui4    = __attribute__((ext_vector_type(4))) unsigned int;
using f4v    = __attribute__((ext_vector_type(4))) float;
using u16x4  = __attribute__((ext_vector_type(4))) unsigned short;
using u16x8  = __attribute__((ext_vector_type(8))) unsigned short;

__device__ __forceinline__ float bf2f(unsigned short u) {
  unsigned int x = ((unsigned int)u) << 16;
  return __builtin_bit_cast(float, x);
}
__device__ __forceinline__ unsigned short f2bf(float f) {
  unsigned int u = __builtin_bit_cast(unsigned int, f);
  u += 0x7fffu + ((u >> 16) & 1u);
  return (unsigned short)(u >> 16);
}
__device__ __forceinline__ float sigmoidf_(float x) { return 1.f / (1.f + __expf(-x)); }

// async global->LDS DMA, 16B per lane; lds dest must be wave-uniform base (+lane*16 implicit)
__device__ __forceinline__ void async_copy16(const unsigned short* __restrict__ g,
                                             unsigned short* l) {
  __builtin_amdgcn_global_load_lds((const __attribute__((address_space(1))) unsigned int*)g,
                                   (__attribute__((address_space(3))) unsigned int*)l, 16, 0, 0);
}

// ---------- dtype detector: flag=1 if inputs are fp32, 0 if bf16 ----------
__global__ void detect_dtype(const unsigned short* __restrict__ hs, int* __restrict__ flag) {
  int tid = threadIdx.x;  // 256 threads
  int cnt = 0;
  for (int i = tid; i < 1024; i += 256) {
    int e = (hs[i] >> 7) & 0xFF;
    if (e >= 134) cnt++;
  }
  #pragma unroll
  for (int off = 32; off; off >>= 1) cnt += __shfl_xor(cnt, off);
  __shared__ int red[4];
  if ((tid & 63) == 0) red[tid >> 6] = cnt;
  __syncthreads();
  if (tid == 0) *flag = (red[0] + red[1] + red[2] + red[3] > 100) ? 1 : 0;
}

// ---------- convert hidden_states -> canonical bf16 ----------
__global__ void convert_hs4(const void* __restrict__ src, unsigned short* __restrict__ dst,
                            const int* __restrict__ flag) {
  size_t i = ((size_t)blockIdx.x * 256 + threadIdx.x) * 4;
  if (*flag) {
    f4v v = *(const f4v*)((const float*)src + i);
    u16x4 o;
    o.x = f2bf(v[0]); o.y = f2bf(v[1]); o.z = f2bf(v[2]); o.w = f2bf(v[3]);
    *(u16x4*)(dst + i) = o;
  } else {
    *(u16x4*)(dst + i) = *(const u16x4*)((const unsigned short*)src + i);
  }
}

// ---------- convert 7 small arrays -> canonical fp32 ----------
// conv weights (a=0,1,2) are additionally TRANSPOSED: in [C][4] -> out [4][C]
__global__ void convert_small(const void* s0, const void* s1, const void* s2,
                              const void* s3, const void* s4, const void* s5, const void* s6,
                              float* d0, float* d1, float* d2, float* d3, float* d4,
                              float* d5, float* d6, const int* __restrict__ flag) {
  const int sizes[7] = {KD * 4, KD * 4, VD * 4, NHh, NHh, NHh, DVh};
  int a = blockIdx.y;
  const void* s; float* d;
  switch (a) {
    case 0: s = s0; d = d0; break;  case 1: s = s1; d = d1; break;
    case 2: s = s2; d = d2; break;  case 3: s = s3; d = d3; break;
    case 4: s = s4; d = d4; break;  case 5: s = s5; d = d5; break;
    default: s = s6; d = d6; break;
  }
  int i = blockIdx.x * 256 + threadIdx.x;
  if (i >= sizes[a]) return;
  float v = (*flag) ? ((const float*)s)[i] : bf2f(((const unsigned short*)s)[i]);
  if (a < 3) {
    int C = (a == 2) ? VD : KD;
    d[(i & 3) * C + (i >> 2)] = v;   // transposed [j][c]
  } else {
    d[i] = v;
  }
}

// ---------- weight transpose+convert: in [R][C] (flag dtype) -> out bf16 [C][R] ----------
__global__ void transpose_conv(const void* __restrict__ in, unsigned short* __restrict__ out,
                               int R, int C, const int* __restrict__ flag) {
  __shared__ unsigned short tile[32][33];
  int f = *flag;
  int c0 = blockIdx.x * 32, r0 = blockIdx.y * 32;
  int tx = threadIdx.x & 31, ty = threadIdx.x >> 5;
  #pragma unroll
  for (int i = 0; i < 32; i += 8) {
    int r = r0 + ty + i, c = c0 + tx;
    unsigned short v = 0;
    if (r < R && c < C)
      v = f ? f2bf(((const float*)in)[(size_t)r * C + c])
            : ((const unsigned short*)in)[(size_t)r * C + c];
    tile[ty + i][tx] = v;
  }
  __syncthreads();
  #pragma unroll
  for (int i = 0; i < 32; i += 8) {
    int c = c0 + ty + i, r = r0 + tx;
    if (c < C && r < R) out[(size_t)c * R + r] = tile[tx][ty + i];
  }
}

// ---------- MFMA GEMM: C[M,N] = A[M,K] * B[K,N], BT = B^T [N,K] ----------
// Round 4: 128^2 tile / 256 thr / 64KB LDS (2 blocks/CU for implicit overlap)
// + T4 counted vmcnt: 2-tile lookahead, drain only tile t (vmcnt(8)), raw
// barriers; T1 bijective XCD swizzle (grids all %8==0); verified XOR LDS swizzle.
// Per iter: vmcnt(8) -> barrier -> compute(buf t) -> barrier -> stage(t+2).
// f32mode: 0=bf16, 1=f32, 2=flag-selected, 3=fused q|k|v|g routing (1536-col regions).
#define BMt 128
#define BNt 128
#define BKt 64

__global__ __launch_bounds__(256, 2) void gemm_bt(
    const unsigned short* __restrict__ Ag,
    const unsigned short* __restrict__ BTg,
    void* __restrict__ Cg,
    int M, int N, int K, int f32mode, const int* __restrict__ flag) {
  __shared__ __align__(16) unsigned short As[2][BMt * BKt];
  __shared__ __align__(16) unsigned short Bs[2][BNt * BKt];
  // XCD-aware bijective block swizzle (requires nwg % 8 == 0; all our grids are)
  const int gx = gridDim.x;
  const int nwg = gx * gridDim.y;
  const int lin = blockIdx.y * gx + blockIdx.x;
  const int swz = (lin & 7) * (nwg >> 3) + (lin >> 3);
  const int bx = swz % gx, by = swz / gx;
  const int tid = threadIdx.x;
  const int wave = tid >> 6, lane = tid & 63;
  const int wr = wave >> 1, wc = wave & 1;
  const int lrow = lane & 15, lq = lane >> 4;
  const int row0 = bx * BMt;
  const int bcol0 = by * BNt;
  // C routing
  unsigned short* Cb = (unsigned short*)Cg;
  int col0 = bcol0, Nst = N;
  if (f32mode == 3) {
    int region = bcol0 / 1536;
    Cb += (size_t)region * (size_t)M_ * 1536;
    col0 = bcol0 - region * 1536;
    Nst = 1536;
  }
  f32x4 acc[4][4] = {};
  // staging: chunk c in [0,1024): r=c>>3, LDS slot u=c&7 holds global slot u^(r&7)
  auto stage = [&](int sb, int k0) {
    #pragma unroll
    for (int i = 0; i < 4; i++) {
      int c = i * 256 + tid;
      int r = c >> 3;
      int kk = ((c & 7) ^ (r & 7)) << 3;   // pre-swizzled source slot
      int ldsbase = (i * 256 + wave * 64) * 8;   // wave-uniform elem offset
      async_copy16(&Ag[(size_t)(row0 + r) * K + k0 + kk], &As[sb][ldsbase]);
      async_copy16(&BTg[(size_t)(bcol0 + r) * K + k0 + kk], &Bs[sb][ldsbase]);
    }
  };
  const int NT = K / BKt;
  stage(0, 0);
  if (NT > 1) stage(1, BKt);
  for (int t = 0; t < NT; t++) {
    // Drain only tile t's 8 loads (per-wave oldest); tile t+1's stay in flight.
    if (t + 1 < NT) asm volatile("s_waitcnt vmcnt(8)" ::: "memory");
    else            asm volatile("s_waitcnt vmcnt(0)" ::: "memory");
    __builtin_amdgcn_s_barrier();       // all waves' tile-t loads are in LDS
    const int cur = t & 1;
    #pragma unroll
    for (int ks = 0; ks < BKt; ks += 32) {
      bf16x8 af[4], bfr[4];
      #pragma unroll
      for (int i = 0; i < 4; i++) {
        int ra = wr * 64 + i * 16 + lrow;
        int sa = ((ks >> 3) + lq) ^ (ra & 7);
        af[i]  = *(const bf16x8*)&As[cur][ra * BKt + (sa << 3)];
        int rb = wc * 64 + i * 16 + lrow;
        int sb2 = ((ks >> 3) + lq) ^ (rb & 7);
        bfr[i] = *(const bf16x8*)&Bs[cur][rb * BKt + (sb2 << 3)];
      }
      __builtin_amdgcn_s_setprio(1);
      #pragma unroll
      for (int mi = 0; mi < 4; mi++)
        #pragma unroll
        for (int ni = 0; ni < 4; ni++)
          acc[mi][ni] = __builtin_amdgcn_mfma_f32_16x16x32_bf16(af[mi], bfr[ni], acc[mi][ni], 0, 0, 0);
      __builtin_amdgcn_s_setprio(0);
    }
    __builtin_amdgcn_s_barrier();       // all waves done reading buffer cur
    if (t + 2 < NT) stage(cur, (t + 2) * BKt);   // buffer released by barrier
  }
  bool f32 = (f32mode == 1) || (f32mode == 2 && *flag != 0);
  #pragma unroll
  for (int mi = 0; mi < 4; mi++)
    #pragma unroll
    for (int ni = 0; ni < 4; ni++)
      #pragma unroll
      for (int r = 0; r < 4; r++) {
        int rr = row0 + wr * 64 + mi * 16 + lq * 4 + r;
        int cc = col0 + wc * 64 + ni * 16 + lrow;
        float v = acc[mi][ni][r];
        if (f32) ((float*)Cg)[(size_t)rr * N + cc] = v;
        else     Cb[(size_t)rr * Nst + cc] = f2bf(v);
      }
}

// ---------- gk/beta from fp32 logits [M][128] (cols 0..11 gk, 12..23 beta) ----------
__global__ void gkbeta_kernel(const float* __restrict__ logits,
                              const float* __restrict__ bb,
                              const float* __restrict__ A_log,
                              const float* __restrict__ dt_bias,
                              float* __restrict__ gkb, float* __restrict__ betab) {
  int idx = blockIdx.x * 256 + threadIdx.x;   // m*24 + j
  int m = idx / 24, j = idx - m * 24;
  float x = logits[(size_t)m * 128 + j];
  if (j < 12) {
    float t = x + dt_bias[j];
    float sp = (t > 20.f) ? t : log1pf(__expf(t));
    gkb[m * NHh + j] = -__expf(A_log[j]) * sp;
  } else {
    betab[m * NHh + (j - 12)] = sigmoidf_(x + bb[j - 12]);
  }
}

// ---------- causal dwconv(K=4) + silu + per-head l2norm (q/k, strided src) ----------
__global__ __launch_bounds__(192) void conv_qk_kernel(
    const unsigned short* __restrict__ raw, int rstride,
    const float* __restrict__ w,
    unsigned short* __restrict__ outp) {
  int tid = threadIdx.x;
  int rib = tid / 96, within = tid - rib * 96;   // row-in-block, 0..95
  int bl = blockIdx.x * 2 + rib;
  int c = within * 8;                             // channel base 0..760
  int l = bl & (L_ - 1);
  float acc[8] = {};
  #pragma unroll
  for (int j = 0; j < 4; j++) {
    int ll = l - 3 + j;
    if (ll >= 0) {
      u16x8 v = *(const u16x8*)&raw[(size_t)(bl - 3 + j) * rstride + c];
      f4v w0 = *(const f4v*)&w[j * KD + c];
      f4v w1 = *(const f4v*)&w[j * KD + c + 4];
      #pragma unroll
      for (int e = 0; e < 4; e++) acc[e] += bf2f(v[e]) * w0[e];
      #pragma unroll
      for (int e = 0; e < 4; e++) acc[4 + e] += bf2f(v[4 + e]) * w1[e];
    }
  }
  float x[8], ss = 0.f;
  #pragma unroll
  for (int e = 0; e < 8; e++) {
    float a = acc[e];
    x[e] = a * sigmoidf_(a);
    ss += x[e] * x[e];
  }
  #pragma unroll
  for (int off = 1; off <= 4; off <<= 1) ss += __shfl_xor(ss, off);
  float inv = 1.f / fmaxf(sqrtf(ss), 1e-12f);
  u16x8 o;
  #pragma unroll
  for (int e = 0; e < 8; e++) o[e] = f2bf(x[e] * inv);
  *(u16x8*)&outp[(size_t)bl * KD + c] = o;
}

// ---------- causal dwconv(K=4) + silu for v ----------
__global__ void conv_v_kernel(const unsigned short* __restrict__ raw,
                              const float* __restrict__ w,
                              unsigned short* __restrict__ outp) {
  int idx = blockIdx.x * 256 + threadIdx.x;   // M_ * 192 tasks
  int bl = idx / 192;
  int c = (idx - bl * 192) * 8;
  int l = bl & (L_ - 1);
  float acc[8] = {};
  #pragma unroll
  for (int j = 0; j < 4; j++) {
    int ll = l - 3 + j;
    if (ll >= 0) {
      u16x8 v = *(const u16x8*)&raw[(size_t)(bl - 3 + j) * VD + c];
      f4v w0 = *(const f4v*)&w[j * VD + c];
      f4v w1 = *(const f4v*)&w[j * VD + c + 4];
      #pragma unroll
      for (int e = 0; e < 4; e++) acc[e] += bf2f(v[e]) * w0[e];
      #pragma unroll
      for (int e = 0; e < 4; e++) acc[4 + e] += bf2f(v[4 + e]) * w1[e];
    }
  }
  u16x8 o;
  #pragma unroll
  for (int e = 0; e < 8; e++) {
    float a = acc[e];
    o[e] = f2bf(a * sigmoidf_(a));
  }
  *(u16x8*)&outp[(size_t)bl * VD + c] = o;
}

// ================= CHUNKED GATED DELTA RULE =================
// ---------- Phase 1: per-chunk precompute (parallel, 1536 blocks) ----------
__global__ __launch_bounds__(256) void phase1_kernel(
    const unsigned short* __restrict__ kb, const unsigned short* __restrict__ vb,
    const float* __restrict__ gkb, const float* __restrict__ betab,
    unsigned short* __restrict__ U0g, unsigned short* __restrict__ Wmg,
    float* __restrict__ Gamg) {
  int cid = blockIdx.x;
  int c = cid & (NC - 1), bh = cid >> 5;
  int h = bh % NHh, b = bh / NHh;
  int bl0 = b * L_ + (c << 6);
  __shared__ __align__(16) unsigned short K_lds[64][72];
  __shared__ __align__(16) unsigned short Ab[64][72];
  __shared__ __align__(16) unsigned short Tb[64][72];
  __shared__ __align__(16) unsigned short TbT[64][72];
  __shared__ __align__(16) unsigned short Qt[64][40];
  __shared__ __align__(16) unsigned short Mpad[16][40];
  __shared__ __align__(16) unsigned short RHSt[192][72];
  __shared__ float G_lds[64], beta_lds[64], besc_lds[64];
  int tid = threadIdx.x;
  int wave = tid >> 6, lane = tid & 63, lq = lane >> 4, lrow = lane & 15;
  {
    u16x4 z = {};
    unsigned short* tb = &Tb[0][0];  unsigned short* tt = &TbT[0][0];
    for (int i = tid * 4; i < 64 * 72; i += 1024) {
      *(u16x4*)&tb[i] = z;  *(u16x4*)&tt[i] = z;
    }
    unsigned short* qt = &Qt[0][0];
    for (int i = tid * 4; i < 64 * 40; i += 1024) *(u16x4*)&qt[i] = z;
    if (tid < 160) *(u16x4*)&(&Mpad[0][0])[tid * 4] = z;
  }
  {
    int j = tid >> 2, d0 = (tid & 3) << 4;
    const ui4* src = (const ui4*)&kb[(size_t)(bl0 + j) * KD + h * 64 + d0];
    *(ui4*)&K_lds[j][d0]     = src[0];
    *(ui4*)&K_lds[j][d0 + 8] = src[1];
  }
  if (tid < 64) {
    float g  = gkb[(size_t)(bl0 + tid) * NHh + h];
    float bt = betab[(size_t)(bl0 + tid) * NHh + h];
    #pragma unroll
    for (int off = 1; off < 64; off <<= 1) {
      int src = lane - off;
      float y = __shfl(g, src < 0 ? 0 : src);
      if (lane >= off) g += y;
    }
    G_lds[tid]    = g;
    beta_lds[tid] = bt;
    besc_lds[tid] = bt * __expf(g);
    Gamg[(size_t)cid * 64 + tid] = g;
  }
  __syncthreads();
  #pragma unroll
  for (int mt = 0; mt < 4; mt++) {
    f32x4 acc = {};
    #pragma unroll
    for (int ks = 0; ks < 2; ks++) {
      bf16x8 a  = *(const bf16x8*)&K_lds[wave * 16 + lrow][ks * 32 + lq * 8];
      bf16x8 b2 = *(const bf16x8*)&K_lds[mt * 16 + lrow][ks * 32 + lq * 8];
      acc = __builtin_amdgcn_mfma_f32_16x16x32_bf16(a, b2, acc, 0, 0, 0);
    }
    #pragma unroll
    for (int r = 0; r < 4; r++) {
      int j = wave * 16 + lq * 4 + r, m = mt * 16 + lrow;
      Ab[j][m] = (m < j) ? f2bf(beta_lds[j] * __expf(G_lds[j] - G_lds[m]) * acc[r])
                         : (unsigned short)0;
    }
  }
  __syncthreads();
  if (wave == 0) {
    int blk = lq, cc = lrow, base = blk * 16;
    float t[16];
    t[0] = (cc == 0) ? 1.f : 0.f;
    #pragma unroll
    for (int j = 1; j < 16; j++) {
      float s = 0.f;
      #pragma unroll
      for (int m = 0; m < j; m++)
        s += bf2f(Ab[base + j][base + m]) * t[m];
      t[j] = ((cc == j) ? 1.f : 0.f) - s;
    }
    #pragma unroll
    for (int j = 0; j < 16; j++) {
      unsigned short bv = f2bf(t[j]);
      Tb[base + j][base + cc]  = bv;
      TbT[base + cc][base + j] = bv;
    }
  } else {
    int r = tid - 64;   // 0..191
    if (r < 128) {
      const unsigned short* vp = &vb[(size_t)bl0 * VD + h * 128 + r];
      for (int j = 0; j < 64; j++)
        RHSt[r][j] = f2bf(beta_lds[j] * bf2f(vp[(size_t)j * VD]));
    } else {
      int d = r - 128;
      for (int j = 0; j < 64; j++)
        RHSt[r][j] = f2bf(besc_lds[j] * bf2f(K_lds[j][d]));
    }
  }
  __syncthreads();
  #pragma unroll
  for (int lvl = 1; lvl < 4; lvl++) {
    {
      int m = tid >> 4, k = tid & 15;
      Ab[lvl * 16 + m][lvl * 16 + k] = 0;
      Mpad[m][k] = Tb[lvl * 16 + m][lvl * 16 + k];
    }
    __syncthreads();
    f32x4 accP = {};
    #pragma unroll
    for (int ks2 = 0; ks2 < 2; ks2++) {
      bf16x8 a  = *(const bf16x8*)&Ab[lvl * 16 + lrow][ks2 * 32 + lq * 8];
      bf16x8 b2 = *(const bf16x8*)&TbT[wave * 16 + lrow][ks2 * 32 + lq * 8];
      accP = __builtin_amdgcn_mfma_f32_16x16x32_bf16(a, b2, accP, 0, 0, 0);
    }
    {
      int col = wave * 16 + lrow;
      u16x4 qp;
      #pragma unroll
      for (int r = 0; r < 4; r++) {
        int krow = lq * 4 + r;
        float e = (col == lvl * 16 + krow) ? 1.f : 0.f;
        ((unsigned short*)&qp)[r] = f2bf(e - accP[r]);
      }
      *(u16x4*)&Qt[col][lq * 4] = qp;
    }
    __syncthreads();
    {
      bf16x8 am = *(const bf16x8*)&Mpad[lrow][lq * 8];
      bf16x8 bq = *(const bf16x8*)&Qt[wave * 16 + lrow][lq * 8];
      f32x4 accR = {};
      accR = __builtin_amdgcn_mfma_f32_16x16x32_bf16(am, bq, accR, 0, 0, 0);
      #pragma unroll
      for (int r = 0; r < 4; r++) {
        int row = lvl * 16 + lq * 4 + r, col = wave * 16 + lrow;
        unsigned short bv = f2bf(accR[r]);
        Tb[row][col]  = bv;
        TbT[col][row] = bv;
      }
    }
    __syncthreads();
  }
  bf16x8 af0 = *(const bf16x8*)&Tb[wave * 16 + lrow][lq * 8];
  bf16x8 af1 = *(const bf16x8*)&Tb[wave * 16 + lrow][32 + lq * 8];
  #pragma unroll
  for (int nt = 0; nt < 12; nt++) {
    f32x4 acc = {};
    bf16x8 b0 = *(const bf16x8*)&RHSt[nt * 16 + lrow][lq * 8];
    bf16x8 b1 = *(const bf16x8*)&RHSt[nt * 16 + lrow][32 + lq * 8];
    acc = __builtin_amdgcn_mfma_f32_16x16x32_bf16(af0, b0, acc, 0, 0, 0);
    acc = __builtin_amdgcn_mfma_f32_16x16x32_bf16(af1, b1, acc, 0, 0, 0);
    #pragma unroll
    for (int r = 0; r < 4; r++) {
      int i = wave * 16 + lq * 4 + r;
      int col = nt * 16 + lrow;
      if (nt < 8) U0g[(size_t)cid * 8192 + i * 128 + col] = f2bf(acc[r]);
      else        Wmg[(size_t)cid * 4096 + i * 64 + (col - 128)] = f2bf(acc[r]);
    }
  }
}

// ---------- Phase 2: inter-chunk state recurrence, v-split (192 blocks) ----------
__global__ __launch_bounds__(256) void phase2_kernel(
    const unsigned short* __restrict__ kb,
    const unsigned short* __restrict__ U0g, const unsigned short* __restrict__ Wmg,
    const float* __restrict__ Gamg, unsigned short* __restrict__ P0g) {
  int blk = blockIdx.x;              // bh*4 + vc
  int vc = blk & 3, bh = blk >> 2;
  int h = bh % NHh, b = bh / NHh;
  __shared__ __align__(16) unsigned short P_bf[32][72];    // S0 slice [v][d]
  __shared__ __align__(16) unsigned short Wm_lds[64][72];  // [j][d]
  __shared__ __align__(16) unsigned short Ktmp[64][72];    // [j][d]
  __shared__ __align__(16) unsigned short KpT_lds[64][72]; // [d][j]
  __shared__ __align__(16) unsigned short U0_lds[64][40];  // [j][v32]
  __shared__ __align__(16) unsigned short UT_lds[32][72];  // [v][j]
  __shared__ float G2[64];
  int tid = threadIdx.x;
  int wave = tid >> 6, lane = tid & 63, lq = lane >> 4, lrow = lane & 15;
  int vt = wave & 1, dbase = (wave >> 1) * 2;
  f32x4 P[2] = {};
  int pj = tid >> 2, px = (tid & 3) << 4;   // Wm/K: 32B per thread
  int pv = (tid & 3) << 3;                  // U0: 16B per thread (8 shorts)
  ui4 pf_wm0, pf_wm1, pf_k0, pf_k1, pf_u0;
  float pf_g = 0.f;
  {
    size_t cid0 = (size_t)bh * NC;
    int bl0 = b * L_;
    pf_wm0 = *(const ui4*)&Wmg[cid0 * 4096 + pj * 64 + px];
    pf_wm1 = *(const ui4*)&Wmg[cid0 * 4096 + pj * 64 + px + 8];
    pf_k0  = *(const ui4*)&kb[(size_t)(bl0 + pj) * KD + h * 64 + px];
    pf_k1  = *(const ui4*)&kb[(size_t)(bl0 + pj) * KD + h * 64 + px + 8];
    pf_u0  = *(const ui4*)&U0g[cid0 * 8192 + pj * 128 + vc * 32 + pv];
    if (tid < 64) pf_g = Gamg[cid0 * 64 + tid];
  }
  for (int c = 0; c < NC; c++) {
    size_t cid = (size_t)bh * NC + c;
    #pragma unroll
    for (int di = 0; di < 2; di++)
      #pragma unroll
      for (int r = 0; r < 4; r++)
        P_bf[vt * 16 + lq * 4 + r][(dbase + di) * 16 + lrow] = f2bf(P[di][r]);
    *(ui4*)&Wm_lds[pj][px]     = pf_wm0;
    *(ui4*)&Wm_lds[pj][px + 8] = pf_wm1;
    *(ui4*)&Ktmp[pj][px]       = pf_k0;
    *(ui4*)&Ktmp[pj][px + 8]   = pf_k1;
    *(ui4*)&U0_lds[pj][pv]     = pf_u0;
    if (tid < 64) G2[tid] = pf_g;
    __syncthreads();
    float gend = __expf(G2[63]);
    {
      int v = tid >> 3, d8 = (tid & 7) << 3;
      *(ui4*)&P0g[cid * 8192 + (size_t)(vc * 32 + v) * 64 + d8] = *(const ui4*)&P_bf[v][d8];
    }
    if (c + 1 < NC) {
      size_t cid1 = cid + 1;
      int bl1 = b * L_ + ((c + 1) << 6);
      pf_wm0 = *(const ui4*)&Wmg[cid1 * 4096 + pj * 64 + px];
      pf_wm1 = *(const ui4*)&Wmg[cid1 * 4096 + pj * 64 + px + 8];
      pf_k0  = *(const ui4*)&kb[(size_t)(bl1 + pj) * KD + h * 64 + px];
      pf_k1  = *(const ui4*)&kb[(size_t)(bl1 + pj) * KD + h * 64 + px + 8];
      pf_u0  = *(const ui4*)&U0g[cid1 * 8192 + pj * 128 + vc * 32 + pv];
      if (tid < 64) pf_g = Gamg[cid1 * 64 + tid];
    }
    {
      int d = tid & 63, j0 = (tid >> 6) << 4;
      float Ge = G2[63];
      #pragma unroll
      for (int i = 0; i < 16; i++) {
        int j = j0 + i;
        KpT_lds[d][j] = f2bf(__expf(Ge - G2[j]) * bf2f(Ktmp[j][d]));
      }
    }
    #pragma unroll
    for (int vt2 = 0; vt2 < 2; vt2++) {
      f32x4 acc = {};
      #pragma unroll
      for (int ks2 = 0; ks2 < 2; ks2++) {
        bf16x8 a  = *(const bf16x8*)&Wm_lds[wave * 16 + lrow][ks2 * 32 + lq * 8];
        bf16x8 b2 = *(const bf16x8*)&P_bf[vt2 * 16 + lrow][ks2 * 32 + lq * 8];
        acc = __builtin_amdgcn_mfma_f32_16x16x32_bf16(a, b2, acc, 0, 0, 0);
      }
      u16x4 p;
      #pragma unroll
      for (int r = 0; r < 4; r++) {
        int j = wave * 16 + lq * 4 + r;
        ((unsigned short*)&p)[r] = f2bf(bf2f(U0_lds[j][vt2 * 16 + lrow]) - acc[r]);
      }
      *(u16x4*)&UT_lds[vt2 * 16 + lrow][wave * 16 + lq * 4] = p;
    }
    __syncthreads();
    #pragma unroll
    for (int di = 0; di < 2; di++) {
      f32x4 acc = P[di];
      #pragma unroll
      for (int r = 0; r < 4; r++) acc[r] *= gend;
      #pragma unroll
      for (int ks2 = 0; ks2 < 2; ks2++) {
        bf16x8 a  = *(const bf16x8*)&UT_lds[vt * 16 + lrow][ks2 * 32 + lq * 8];
        bf16x8 b2 = *(const bf16x8*)&KpT_lds[(dbase + di) * 16 + lrow][ks2 * 32 + lq * 8];
        acc = __builtin_amdgcn_mfma_f32_16x16x32_bf16(a, b2, acc, 0, 0, 0);
      }
      P[di] = acc;
    }
  }
}

// ---------- Phase 3: per-chunk output (parallel, 1536 blocks) ----------
__global__ __launch_bounds__(256) void phase3_kernel(
    const unsigned short* __restrict__ qb, const unsigned short* __restrict__ kb,
    const unsigned short* __restrict__ U0g, const unsigned short* __restrict__ Wmg,
    const unsigned short* __restrict__ P0g, const float* __restrict__ Gamg,
    unsigned short* __restrict__ o_raw) {
  int cid = blockIdx.x;
  int c = cid & (NC - 1), bh = cid >> 5;
  int h = bh % NHh, b = bh / NHh;
  int bl0 = b * L_ + (c << 6);
  __shared__ __align__(16) unsigned short Q_lds[64][72];
  __shared__ __align__(16) unsigned short K_lds[64][72];
  __shared__ __align__(16) unsigned short WM_lds[64][72];
  __shared__ __align__(16) unsigned short P0_lds[128][72];
  __shared__ __align__(16) unsigned short U0_lds[64][128];
  __shared__ __align__(16) unsigned short UT_lds[128][72];
  __shared__ float G_lds[64];
  int tid = threadIdx.x;
  int wave = tid >> 6, lane = tid & 63, lq = lane >> 4, lrow = lane & 15;
  {
    int j = tid >> 2, d0 = (tid & 3) << 4;
    const ui4* qs = (const ui4*)&qb[(size_t)(bl0 + j) * KD + h * 64 + d0];
    *(ui4*)&Q_lds[j][d0] = qs[0];  *(ui4*)&Q_lds[j][d0 + 8] = qs[1];
    const ui4* ks = (const ui4*)&kb[(size_t)(bl0 + j) * KD + h * 64 + d0];
    *(ui4*)&K_lds[j][d0] = ks[0];  *(ui4*)&K_lds[j][d0 + 8] = ks[1];
    const ui4* ws = (const ui4*)&Wmg[(size_t)cid * 4096 + j * 64 + d0];
    *(ui4*)&WM_lds[j][d0] = ws[0]; *(ui4*)&WM_lds[j][d0 + 8] = ws[1];
    int v = tid >> 1, e0 = (tid & 1) << 5;
    const ui4* ps = (const ui4*)&P0g[(size_t)cid * 8192 + v * 64 + e0];
    *(ui4*)&P0_lds[v][e0]      = ps[0]; *(ui4*)&P0_lds[v][e0 + 8]  = ps[1];
    *(ui4*)&P0_lds[v][e0 + 16] = ps[2]; *(ui4*)&P0_lds[v][e0 + 24] = ps[3];
    int e1 = tid * 32;
    const ui4* us = (const ui4*)&U0g[(size_t)cid * 8192 + e1];
    ui4* ud = (ui4*)&U0_lds[0][e1];
    ud[0] = us[0]; ud[1] = us[1]; ud[2] = us[2]; ud[3] = us[3];
    if (tid < 64) G_lds[tid] = Gamg[(size_t)cid * 64 + tid];
  }
  __syncthreads();
  #pragma unroll
  for (int nt = 0; nt < 8; nt++) {
    f32x4 acc = {};
    #pragma unroll
    for (int ks2 = 0; ks2 < 2; ks2++) {
      bf16x8 a  = *(const bf16x8*)&WM_lds[wave * 16 + lrow][ks2 * 32 + lq * 8];
      bf16x8 b2 = *(const bf16x8*)&P0_lds[nt * 16 + lrow][ks2 * 32 + lq * 8];
      acc = __builtin_amdgcn_mfma_f32_16x16x32_bf16(a, b2, acc, 0, 0, 0);
    }
    u16x4 p;
    #pragma unroll
    for (int r = 0; r < 4; r++) {
      int j = wave * 16 + lq * 4 + r;
      ((unsigned short*)&p)[r] = f2bf(bf2f(U0_lds[j][nt * 16 + lrow]) - acc[r]);
    }
    *(u16x4*)&UT_lds[nt * 16 + lrow][wave * 16 + lq * 4] = p;
  }
  __syncthreads();
  #pragma unroll
  for (int mt = 0; mt < 4; mt++) {
    f32x4 acc = {};
    #pragma unroll
    for (int ks2 = 0; ks2 < 2; ks2++) {
      bf16x8 a  = *(const bf16x8*)&Q_lds[wave * 16 + lrow][ks2 * 32 + lq * 8];
      bf16x8 b2 = *(const bf16x8*)&K_lds[mt * 16 + lrow][ks2 * 32 + lq * 8];
      acc = __builtin_amdgcn_mfma_f32_16x16x32_bf16(a, b2, acc, 0, 0, 0);
    }
    #pragma unroll
    for (int r = 0; r < 4; r++) {
      int i = wave * 16 + lq * 4 + r, j = mt * 16 + lrow;
      WM_lds[i][j] = (j <= i) ? f2bf(__expf(G_lds[i] - G_lds[j]) * acc[r]) : (unsigned short)0;
    }
  }
  __syncthreads();
  #pragma unroll
  for (int nt = 0; nt < 8; nt++) {
    f32x4 accO = {}, accS = {};
    #pragma unroll
    for (int ks2 = 0; ks2 < 2; ks2++) {
      bf16x8 aM = *(const bf16x8*)&WM_lds[wave * 16 + lrow][ks2 * 32 + lq * 8];
      bf16x8 bU = *(const bf16x8*)&UT_lds[nt * 16 + lrow][ks2 * 32 + lq * 8];
      accO = __builtin_amdgcn_mfma_f32_16x16x32_bf16(aM, bU, accO, 0, 0, 0);
      bf16x8 aQ = *(const bf16x8*)&Q_lds[wave * 16 + lrow][ks2 * 32 + lq * 8];
      bf16x8 bP = *(const bf16x8*)&P0_lds[nt * 16 + lrow][ks2 * 32 + lq * 8];
      accS = __builtin_amdgcn_mfma_f32_16x16x32_bf16(aQ, bP, accS, 0, 0, 0);
    }
    #pragma unroll
    for (int r = 0; r < 4; r++) {
      int i = wave * 16 + lq * 4 + r;
      float o = accO[r] + __expf(G_lds[i]) * accS[r];
      o_raw[(size_t)(bl0 + i) * VD + h * 128 + nt * 16 + lrow] = f2bf(o);
    }
  }
}

// ---------- rmsnorm + gnorm_w * silu(g), in-place on o_raw ----------
__global__ void norm_gate_kernel(unsigned short* __restrict__ o_raw,
                                 const unsigned short* __restrict__ g,
                                 const float* __restrict__ gnw) {
  int tid = threadIdx.x;
  int r = blockIdx.x * 16 + (tid >> 4);
  int v = (tid & 15) * 8;
  u16x8 xo = *(const u16x8*)&o_raw[(size_t)r * DVh + v];
  u16x8 xg = *(const u16x8*)&g[(size_t)r * DVh + v];
  float x[8], ss = 0.f;
  #pragma unroll
  for (int e = 0; e < 8; e++) {
    x[e] = bf2f(xo[e]);
    ss += x[e] * x[e];
  }
  #pragma unroll
  for (int off = 1; off <= 8; off <<= 1) ss += __shfl_xor(ss, off);
  float inv = rsqrtf(ss * (1.f / (float)DVh) + 1e-5f);
  f4v w0 = *(const f4v*)&gnw[v];
  f4v w1 = *(const f4v*)&gnw[v + 4];
  u16x8 o;
  #pragma unroll
  for (int e = 0; e < 8; e++) {
    float gv = bf2f(xg[e]);
    float wv = (e < 4) ? w0[e] : w1[e - 4];
    o[e] = f2bf(x[e] * inv * wv * (gv * sigmoidf_(gv)));
  }
  *(u16x8*)&o_raw[(size_t)r * DVh + v] = o;
}

// ---------- host launch ----------
extern "C" void kernel_launch(void* const* d_in, const int* in_sizes, int n_in,
                              void* d_out, int out_size, void* d_ws, size_t ws_size,
                              hipStream_t stream) {
  const void* hs      = d_in[0];
  const void* Wq      = d_in[1];
  const void* Wk      = d_in[2];
  const void* Wv      = d_in[3];
  const void* Wg      = d_in[4];
  const void* Wgk     = d_in[5];
  const void* Wb      = d_in[6];
  const void* bb      = d_in[7];
  const void* cq      = d_in[8];
  const void* ck      = d_in[9];
  const void* cv      = d_in[10];
  const void* A_log   = d_in[11];
  const void* gnorm_w = d_in[12];
  const void* Wo      = d_in[13];
  const void* dt_bias = d_in[14];

  char* wsB = (char*)d_ws;
  size_t off = 0;
  auto walloc = [&](size_t bytes) -> char* {
    char* p = wsB + off;
    off += (bytes + 1023) & ~(size_t)1023;
    return p;
  };
  int* flag = (int*)walloc(1024);
  // NOTE: WqT..WgT must stay contiguous (fused BT of [4608][1024]); all sizes
  // are multiples of 1024 so walloc adds no padding between them.
  unsigned short* WqT   = (unsigned short*)walloc((size_t)KD * H_ * 2);
  unsigned short* WkT   = (unsigned short*)walloc((size_t)KD * H_ * 2);
  unsigned short* WvT   = (unsigned short*)walloc((size_t)VD * H_ * 2);
  unsigned short* WgT   = (unsigned short*)walloc((size_t)VD * H_ * 2);
  unsigned short* WgkbT = (unsigned short*)walloc((size_t)128 * H_ * 2);
  unsigned short* WoT   = (unsigned short*)walloc((size_t)H_ * VD * 2);
  float* cqf   = (float*)walloc((size_t)KD * 4 * 4);
  float* ckf   = (float*)walloc((size_t)KD * 4 * 4);
  float* cvf   = (float*)walloc((size_t)VD * 4 * 4);
  float* bbf   = (float*)walloc(NHh * 4);
  float* A_logf= (float*)walloc(NHh * 4);
  float* dtf   = (float*)walloc(NHh * 4);
  float* gnwf  = (float*)walloc(DVh * 4);
  float* gkb   = (float*)walloc((size_t)M_ * NHh * 4);
  float* betab = (float*)walloc((size_t)M_ * NHh * 4);
  float* Gamg  = (float*)walloc((size_t)NCID * 64 * 4);
  unsigned short* c_hs  = (unsigned short*)walloc((size_t)M_ * H_ * 2);
  // qkraw/vraw/gbuf must stay contiguous (fused GEMM C routing).
  unsigned short* qkraw = (unsigned short*)walloc((size_t)M_ * 1536 * 2);
  unsigned short* vraw  = (unsigned short*)walloc((size_t)M_ * VD * 2);
  unsigned short* gbuf  = (unsigned short*)walloc((size_t)M_ * VD * 2);
  unsigned short* qb    = (unsigned short*)walloc((size_t)M_ * KD * 2);
  unsigned short* kb    = (unsigned short*)walloc((size_t)M_ * KD * 2);
  unsigned short* vb    = (unsigned short*)walloc((size_t)M_ * VD * 2);
  // overlays (safe by launch order):
  float*          logits32 = (float*)vraw;   // consumed by gkbeta BEFORE fused GEMM
  unsigned short* Wmg   = c_hs;
  unsigned short* U0g   = qkraw;
  unsigned short* o_raw = vraw;
  unsigned short* P0g   = vb;

  // 0. dtype detection + canonicalization
  detect_dtype<<<1, 256, 0, stream>>>((const unsigned short*)hs, flag);
  convert_small<<<dim3(24, 7), 256, 0, stream>>>(cq, ck, cv, bb, A_log, dt_bias, gnorm_w,
                                                 cqf, ckf, cvf, bbf, A_logf, dtf, gnwf, flag);
  transpose_conv<<<dim3(KD / 32, H_ / 32), 256, 0, stream>>>(Wq, WqT, H_, KD, flag);
  transpose_conv<<<dim3(KD / 32, H_ / 32), 256, 0, stream>>>(Wk, WkT, H_, KD, flag);
  transpose_conv<<<dim3(VD / 32, H_ / 32), 256, 0, stream>>>(Wv, WvT, H_, VD, flag);
  transpose_conv<<<dim3(VD / 32, H_ / 32), 256, 0, stream>>>(Wg, WgT, H_, VD, flag);
  transpose_conv<<<dim3(1, H_ / 32), 256, 0, stream>>>(Wgk, WgkbT, H_, NHh, flag);
  transpose_conv<<<dim3(1, H_ / 32), 256, 0, stream>>>(Wb, WgkbT + 12 * H_, H_, NHh, flag);
  transpose_conv<<<dim3(H_ / 32, VD / 32), 256, 0, stream>>>(Wo, WoT, VD, H_, flag);
  convert_hs4<<<(M_ * H_) / 1024, 256, 0, stream>>>(hs, c_hs, flag);

  // 1a. gk/beta logits first (logits32 overlays vraw; consume before fused GEMM)
  gemm_bt<<<dim3(M_ / 128, 1), 256, 0, stream>>>(c_hs, WgkbT, logits32, M_, 128, H_, 1, flag);
  gkbeta_kernel<<<(M_ * 24) / 256, 256, 0, stream>>>(logits32, bbf, A_logf, dtf, gkb, betab);
  // 1b. fused q|k|v|g projection: BT = [WqT;WkT;WvT;WgT] = [4608][1024],
  //     C routed per 128-col tile into qkraw / vraw / gbuf (mode 3)
  gemm_bt<<<dim3(M_ / 128, 4608 / 128), 256, 0, stream>>>(c_hs, WqT, qkraw, M_, 4608, H_, 3, flag);

  // 2. conv + silu (+ l2norm for q/k) — vectorized 16B/lane
  conv_qk_kernel<<<M_ / 2, 192, 0, stream>>>(qkraw, 1536, cqf, qb);
  conv_qk_kernel<<<M_ / 2, 192, 0, stream>>>(qkraw + KD, 1536, ckf, kb);
  conv_v_kernel<<<(M_ * 192) / 256, 256, 0, stream>>>(vraw, cvf, vb);

  // 3. chunked gated delta rule
  phase1_kernel<<<NCID, 256, 0, stream>>>(kb, vb, gkb, betab, U0g, Wmg, Gamg);
  phase2_kernel<<<B_ * NHh * 4, 256, 0, stream>>>(kb, U0g, Wmg, Gamg, P0g);
  phase3_kernel<<<NCID, 256, 0, stream>>>(qb, kb, U0g, Wmg, P0g, Gamg, o_raw);

  // 4. rmsnorm + swish gate (in-place on o_raw) — vectorized
  norm_gate_kernel<<<(M_ * NHh) / 16, 256, 0, stream>>>(o_raw, gbuf, gnwf);

  // 5. output projection (dtype-flag-selected store)
  gemm_bt<<<dim3(M_ / 128, H_ / 128), 256, 0, stream>>>(o_raw, WoT, d_out, M_, H_, VD, 2, flag);
}

// Round 5
// 457.393 us; speedup vs baseline: 1.0455x; 1.0287x over previous
//
#include <hip/hip_runtime.h>

// ---------- problem constants ----------
#define B_   4
#define L_   2048
#define H_   1024
#define KD   768
#define VD   1536
#define NHh  12
#define DKh  64
#define DVh  128
#define M_   (B_ * L_)   // 8192 rows
#define NC   32          // chunks per sequence (L/64)
#define NCID (B_ * NHh * NC)  // 1536

using bf16x8 = __attribute__((ext_vector_type(8))) __bf16;
using f32x4  = __attribute__((ext_vector_type(4))) float;
using ui4    = __attribute__((ext_vector_type(4))) unsigned int;
using f4v    = __attribute__((ext_vector_type(4))) float;
using u16x4  = __attribute__((ext_vector_type(4))) unsigned short;
using u16x8  = __attribute__((ext_vector_type(8))) unsigned short;

__device__ __forceinline__ float bf2f(unsigned short u) {
  unsigned int x = ((unsigned int)u) << 16;
  return __builtin_bit_cast(float, x);
}
__device__ __forceinline__ unsigned short f2bf(float f) {
  unsigned int u = __builtin_bit_cast(unsigned int, f);
  u += 0x7fffu + ((u >> 16) & 1u);
  return (unsigned short)(u >> 16);
}
__device__ __forceinline__ float sigmoidf_(float x) { return 1.f / (1.f + __expf(-x)); }

// async global->LDS DMA, 16B per lane; lds dest must be wave-uniform base (+lane*16 implicit)
__device__ __forceinline__ void async_copy16(const unsigned short* __restrict__ g,
                                             unsigned short* l) {
  __builtin_amdgcn_global_load_lds((const __attribute__((address_space(1))) unsigned int*)g,
                                   (__attribute__((address_space(3))) unsigned int*)l, 16, 0, 0);
}

// ---------- dtype detector: flag=1 if inputs are fp32, 0 if bf16 ----------
__global__ void detect_dtype(const unsigned short* __restrict__ hs, int* __restrict__ flag) {
  int tid = threadIdx.x;  // 256 threads
  int cnt = 0;
  for (int i = tid; i < 1024; i += 256) {
    int e = (hs[i] >> 7) & 0xFF;
    if (e >= 134) cnt++;
  }
  #pragma unroll
  for (int off = 32; off; off >>= 1) cnt += __shfl_xor(cnt, off);
  __shared__ int red[4];
  if ((tid & 63) == 0) red[tid >> 6] = cnt;
  __syncthreads();
  if (tid == 0) *flag = (red[0] + red[1] + red[2] + red[3] > 100) ? 1 : 0;
}

// ---------- convert hidden_states -> canonical bf16 ----------
__global__ void convert_hs4(const void* __restrict__ src, unsigned short* __restrict__ dst,
                            const int* __restrict__ flag) {
  size_t i = ((size_t)blockIdx.x * 256 + threadIdx.x) * 4;
  if (*flag) {
    f4v v = *(const f4v*)((const float*)src + i);
    u16x4 o;
    o.x = f2bf(v[0]); o.y = f2bf(v[1]); o.z = f2bf(v[2]); o.w = f2bf(v[3]);
    *(u16x4*)(dst + i) = o;
  } else {
    *(u16x4*)(dst + i) = *(const u16x4*)((const unsigned short*)src + i);
  }
}

// ---------- convert 7 small arrays -> canonical fp32 ----------
// conv weights (a=0,1,2) are additionally TRANSPOSED: in [C][4] -> out [4][C]
__global__ void convert_small(const void* s0, const void* s1, const void* s2,
                              const void* s3, const void* s4, const void* s5, const void* s6,
                              float* d0, float* d1, float* d2, float* d3, float* d4,
                              float* d5, float* d6, const int* __restrict__ flag) {
  const int sizes[7] = {KD * 4, KD * 4, VD * 4, NHh, NHh, NHh, DVh};
  int a = blockIdx.y;
  const void* s; float* d;
  switch (a) {
    case 0: s = s0; d = d0; break;  case 1: s = s1; d = d1; break;
    case 2: s = s2; d = d2; break;  case 3: s = s3; d = d3; break;
    case 4: s = s4; d = d4; break;  case 5: s = s5; d = d5; break;
    default: s = s6; d = d6; break;
  }
  int i = blockIdx.x * 256 + threadIdx.x;
  if (i >= sizes[a]) return;
  float v = (*flag) ? ((const float*)s)[i] : bf2f(((const unsigned short*)s)[i]);
  if (a < 3) {
    int C = (a == 2) ? VD : KD;
    d[(i & 3) * C + (i >> 2)] = v;   // transposed [j][c]
  } else {
    d[i] = v;
  }
}

// ---------- weight transpose+convert: in [R][C] (flag dtype) -> out bf16 [C][R] ----------
__global__ void transpose_conv(const void* __restrict__ in, unsigned short* __restrict__ out,
                               int R, int C, const int* __restrict__ flag) {
  __shared__ unsigned short tile[32][33];
  int f = *flag;
  int c0 = blockIdx.x * 32, r0 = blockIdx.y * 32;
  int tx = threadIdx.x & 31, ty = threadIdx.x >> 5;
  #pragma unroll
  for (int i = 0; i < 32; i += 8) {
    int r = r0 + ty + i, c = c0 + tx;
    unsigned short v = 0;
    if (r < R && c < C)
      v = f ? f2bf(((const float*)in)[(size_t)r * C + c])
            : ((const unsigned short*)in)[(size_t)r * C + c];
    tile[ty + i][tx] = v;
  }
  __syncthreads();
  #pragma unroll
  for (int i = 0; i < 32; i += 8) {
    int c = c0 + ty + i, r = r0 + tx;
    if (c < C && r < R) out[(size_t)c * R + r] = tile[tx][ty + i];
  }
}

// ---------- MFMA GEMM: C[M,N] = A[M,K] * B[K,N], BT = B^T [N,K] ----------
// Round 5: 128^2 tile / 256 thr / 64KB LDS (2 blocks/CU) + T4 counted vmcnt
// (2-tile lookahead, drain only tile t via vmcnt(8), raw barriers) + verified
// XOR LDS swizzle. XCD block swizzle REMOVED (round-4 post-mortem: it caused a
// 4x FETCH_SIZE blowup — A-panel doesn't fit XCD-private L2; natural dispatch
// order keeps the L3-fit working set).
// Per iter: vmcnt(8) -> barrier -> compute(buf t) -> barrier -> stage(t+2).
// f32mode: 0=bf16, 1=f32, 2=flag-selected, 3=fused q|k|v|g routing (1536-col regions).
#define BMt 128
#define BNt 128
#define BKt 64

__global__ __launch_bounds__(256, 2) void gemm_bt(
    const unsigned short* __restrict__ Ag,
    const unsigned short* __restrict__ BTg,
    void* __restrict__ Cg,
    int M, int N, int K, int f32mode, const int* __restrict__ flag) {
  __shared__ __align__(16) unsigned short As[2][BMt * BKt];
  __shared__ __align__(16) unsigned short Bs[2][BNt * BKt];
  const int tid = threadIdx.x;
  const int wave = tid >> 6, lane = tid & 63;
  const int wr = wave >> 1, wc = wave & 1;
  const int lrow = lane & 15, lq = lane >> 4;
  const int row0 = blockIdx.x * BMt;
  const int bcol0 = blockIdx.y * BNt;
  // C routing
  unsigned short* Cb = (unsigned short*)Cg;
  int col0 = bcol0, Nst = N;
  if (f32mode == 3) {
    int region = bcol0 / 1536;
    Cb += (size_t)region * (size_t)M_ * 1536;
    col0 = bcol0 - region * 1536;
    Nst = 1536;
  }
  f32x4 acc[4][4] = {};
  // staging: chunk c in [0,1024): r=c>>3, LDS slot u=c&7 holds global slot u^(r&7)
  auto stage = [&](int sb, int k0) {
    #pragma unroll
    for (int i = 0; i < 4; i++) {
      int c = i * 256 + tid;
      int r = c >> 3;
      int kk = ((c & 7) ^ (r & 7)) << 3;   // pre-swizzled source slot
      int ldsbase = (i * 256 + wave * 64) * 8;   // wave-uniform elem offset
      async_copy16(&Ag[(size_t)(row0 + r) * K + k0 + kk], &As[sb][ldsbase]);
      async_copy16(&BTg[(size_t)(bcol0 + r) * K + k0 + kk], &Bs[sb][ldsbase]);
    }
  };
  const int NT = K / BKt;
  stage(0, 0);
  if (NT > 1) stage(1, BKt);
  for (int t = 0; t < NT; t++) {
    // Drain only tile t's 8 loads (per-wave oldest); tile t+1's stay in flight.
    if (t + 1 < NT) asm volatile("s_waitcnt vmcnt(8)" ::: "memory");
    else            asm volatile("s_waitcnt vmcnt(0)" ::: "memory");
    __builtin_amdgcn_s_barrier();       // all waves' tile-t loads are in LDS
    const int cur = t & 1;
    #pragma unroll
    for (int ks = 0; ks < BKt; ks += 32) {
      bf16x8 af[4], bfr[4];
      #pragma unroll
      for (int i = 0; i < 4; i++) {
        int ra = wr * 64 + i * 16 + lrow;
        int sa = ((ks >> 3) + lq) ^ (ra & 7);
        af[i]  = *(const bf16x8*)&As[cur][ra * BKt + (sa << 3)];
        int rb = wc * 64 + i * 16 + lrow;
        int sb2 = ((ks >> 3) + lq) ^ (rb & 7);
        bfr[i] = *(const bf16x8*)&Bs[cur][rb * BKt + (sb2 << 3)];
      }
      __builtin_amdgcn_s_setprio(1);
      #pragma unroll
      for (int mi = 0; mi < 4; mi++)
        #pragma unroll
        for (int ni = 0; ni < 4; ni++)
          acc[mi][ni] = __builtin_amdgcn_mfma_f32_16x16x32_bf16(af[mi], bfr[ni], acc[mi][ni], 0, 0, 0);
      __builtin_amdgcn_s_setprio(0);
    }
    __builtin_amdgcn_s_barrier();       // all waves done reading buffer cur
    if (t + 2 < NT) stage(cur, (t + 2) * BKt);   // buffer released by barrier
  }
  bool f32 = (f32mode == 1) || (f32mode == 2 && *flag != 0);
  #pragma unroll
  for (int mi = 0; mi < 4; mi++)
    #pragma unroll
    for (int ni = 0; ni < 4; ni++)
      #pragma unroll
      for (int r = 0; r < 4; r++) {
        int rr = row0 + wr * 64 + mi * 16 + lq * 4 + r;
        int cc = col0 + wc * 64 + ni * 16 + lrow;
        float v = acc[mi][ni][r];
        if (f32) ((float*)Cg)[(size_t)rr * N + cc] = v;
        else     Cb[(size_t)rr * Nst + cc] = f2bf(v);
      }
}

// ---------- gk/beta from fp32 logits [M][128] (cols 0..11 gk, 12..23 beta) ----------
__global__ void gkbeta_kernel(const float* __restrict__ logits,
                              const float* __restrict__ bb,
                              const float* __restrict__ A_log,
                              const float* __restrict__ dt_bias,
                              float* __restrict__ gkb, float* __restrict__ betab) {
  int idx = blockIdx.x * 256 + threadIdx.x;   // m*24 + j
  int m = idx / 24, j = idx - m * 24;
  float x = logits[(size_t)m * 128 + j];
  if (j < 12) {
    float t = x + dt_bias[j];
    float sp = (t > 20.f) ? t : log1pf(__expf(t));
    gkb[m * NHh + j] = -__expf(A_log[j]) * sp;
  } else {
    betab[m * NHh + (j - 12)] = sigmoidf_(x + bb[j - 12]);
  }
}

// ---------- causal dwconv(K=4) + silu + per-head l2norm (q/k, strided src) ----------
__global__ __launch_bounds__(192) void conv_qk_kernel(
    const unsigned short* __restrict__ raw, int rstride,
    const float* __restrict__ w,
    unsigned short* __restrict__ outp) {
  int tid = threadIdx.x;
  int rib = tid / 96, within = tid - rib * 96;   // row-in-block, 0..95
  int bl = blockIdx.x * 2 + rib;
  int c = within * 8;                             // channel base 0..760
  int l = bl & (L_ - 1);
  float acc[8] = {};
  #pragma unroll
  for (int j = 0; j < 4; j++) {
    int ll = l - 3 + j;
    if (ll >= 0) {
      u16x8 v = *(const u16x8*)&raw[(size_t)(bl - 3 + j) * rstride + c];
      f4v w0 = *(const f4v*)&w[j * KD + c];
      f4v w1 = *(const f4v*)&w[j * KD + c + 4];
      #pragma unroll
      for (int e = 0; e < 4; e++) acc[e] += bf2f(v[e]) * w0[e];
      #pragma unroll
      for (int e = 0; e < 4; e++) acc[4 + e] += bf2f(v[4 + e]) * w1[e];
    }
  }
  float x[8], ss = 0.f;
  #pragma unroll
  for (int e = 0; e < 8; e++) {
    float a = acc[e];
    x[e] = a * sigmoidf_(a);
    ss += x[e] * x[e];
  }
  #pragma unroll
  for (int off = 1; off <= 4; off <<= 1) ss += __shfl_xor(ss, off);
  float inv = 1.f / fmaxf(sqrtf(ss), 1e-12f);
  u16x8 o;
  #pragma unroll
  for (int e = 0; e < 8; e++) o[e] = f2bf(x[e] * inv);
  *(u16x8*)&outp[(size_t)bl * KD + c] = o;
}

// ---------- causal dwconv(K=4) + silu for v ----------
__global__ void conv_v_kernel(const unsigned short* __restrict__ raw,
                              const float* __restrict__ w,
                              unsigned short* __restrict__ outp) {
  int idx = blockIdx.x * 256 + threadIdx.x;   // M_ * 192 tasks
  int bl = idx / 192;
  int c = (idx - bl * 192) * 8;
  int l = bl & (L_ - 1);
  float acc[8] = {};
  #pragma unroll
  for (int j = 0; j < 4; j++) {
    int ll = l - 3 + j;
    if (ll >= 0) {
      u16x8 v = *(const u16x8*)&raw[(size_t)(bl - 3 + j) * VD + c];
      f4v w0 = *(const f4v*)&w[j * VD + c];
      f4v w1 = *(const f4v*)&w[j * VD + c + 4];
      #pragma unroll
      for (int e = 0; e < 4; e++) acc[e] += bf2f(v[e]) * w0[e];
      #pragma unroll
      for (int e = 0; e < 4; e++) acc[4 + e] += bf2f(v[4 + e]) * w1[e];
    }
  }
  u16x8 o;
  #pragma unroll
  for (int e = 0; e < 8; e++) {
    float a = acc[e];
    o[e] = f2bf(a * sigmoidf_(a));
  }
  *(u16x8*)&outp[(size_t)bl * VD + c] = o;
}

// ================= CHUNKED GATED DELTA RULE =================
// ---------- Phase 1: per-chunk precompute (parallel, 1536 blocks) ----------
__global__ __launch_bounds__(256) void phase1_kernel(
    const unsigned short* __restrict__ kb, const unsigned short* __restrict__ vb,
    const float* __restrict__ gkb, const float* __restrict__ betab,
    unsigned short* __restrict__ U0g, unsigned short* __restrict__ Wmg,
    float* __restrict__ Gamg) {
  int cid = blockIdx.x;
  int c = cid & (NC - 1), bh = cid >> 5;
  int h = bh % NHh, b = bh / NHh;
  int bl0 = b * L_ + (c << 6);
  __shared__ __align__(16) unsigned short K_lds[64][72];
  __shared__ __align__(16) unsigned short Ab[64][72];
  __shared__ __align__(16) unsigned short Tb[64][72];
  __shared__ __align__(16) unsigned short TbT[64][72];
  __shared__ __align__(16) unsigned short Qt[64][40];
  __shared__ __align__(16) unsigned short Mpad[16][40];
  __shared__ __align__(16) unsigned short RHSt[192][72];
  __shared__ float G_lds[64], beta_lds[64], besc_lds[64];
  int tid = threadIdx.x;
  int wave = tid >> 6, lane = tid & 63, lq = lane >> 4, lrow = lane & 15;
  {
    u16x4 z = {};
    unsigned short* tb = &Tb[0][0];  unsigned short* tt = &TbT[0][0];
    for (int i = tid * 4; i < 64 * 72; i += 1024) {
      *(u16x4*)&tb[i] = z;  *(u16x4*)&tt[i] = z;
    }
    unsigned short* qt = &Qt[0][0];
    for (int i = tid * 4; i < 64 * 40; i += 1024) *(u16x4*)&qt[i] = z;
    if (tid < 160) *(u16x4*)&(&Mpad[0][0])[tid * 4] = z;
  }
  {
    int j = tid >> 2, d0 = (tid & 3) << 4;
    const ui4* src = (const ui4*)&kb[(size_t)(bl0 + j) * KD + h * 64 + d0];
    *(ui4*)&K_lds[j][d0]     = src[0];
    *(ui4*)&K_lds[j][d0 + 8] = src[1];
  }
  if (tid < 64) {
    float g  = gkb[(size_t)(bl0 + tid) * NHh + h];
    float bt = betab[(size_t)(bl0 + tid) * NHh + h];
    #pragma unroll
    for (int off = 1; off < 64; off <<= 1) {
      int src = lane - off;
      float y = __shfl(g, src < 0 ? 0 : src);
      if (lane >= off) g += y;
    }
    G_lds[tid]    = g;
    beta_lds[tid] = bt;
    besc_lds[tid] = bt * __expf(g);
    Gamg[(size_t)cid * 64 + tid] = g;
  }
  __syncthreads();
  #pragma unroll
  for (int mt = 0; mt < 4; mt++) {
    f32x4 acc = {};
    #pragma unroll
    for (int ks = 0; ks < 2; ks++) {
      bf16x8 a  = *(const bf16x8*)&K_lds[wave * 16 + lrow][ks * 32 + lq * 8];
      bf16x8 b2 = *(const bf16x8*)&K_lds[mt * 16 + lrow][ks * 32 + lq * 8];
      acc = __builtin_amdgcn_mfma_f32_16x16x32_bf16(a, b2, acc, 0, 0, 0);
    }
    #pragma unroll
    for (int r = 0; r < 4; r++) {
      int j = wave * 16 + lq * 4 + r, m = mt * 16 + lrow;
      Ab[j][m] = (m < j) ? f2bf(beta_lds[j] * __expf(G_lds[j] - G_lds[m]) * acc[r])
                         : (unsigned short)0;
    }
  }
  __syncthreads();
  if (wave == 0) {
    int blk = lq, cc = lrow, base = blk * 16;
    float t[16];
    t[0] = (cc == 0) ? 1.f : 0.f;
    #pragma unroll
    for (int j = 1; j < 16; j++) {
      float s = 0.f;
      #pragma unroll
      for (int m = 0; m < j; m++)
        s += bf2f(Ab[base + j][base + m]) * t[m];
      t[j] = ((cc == j) ? 1.f : 0.f) - s;
    }
    #pragma unroll
    for (int j = 0; j < 16; j++) {
      unsigned short bv = f2bf(t[j]);
      Tb[base + j][base + cc]  = bv;
      TbT[base + cc][base + j] = bv;
    }
  } else {
    int r = tid - 64;   // 0..191
    if (r < 128) {
      const unsigned short* vp = &vb[(size_t)bl0 * VD + h * 128 + r];
      for (int j = 0; j < 64; j++)
        RHSt[r][j] = f2bf(beta_lds[j] * bf2f(vp[(size_t)j * VD]));
    } else {
      int d = r - 128;
      for (int j = 0; j < 64; j++)
        RHSt[r][j] = f2bf(besc_lds[j] * bf2f(K_lds[j][d]));
    }
  }
  __syncthreads();
  #pragma unroll
  for (int lvl = 1; lvl < 4; lvl++) {
    {
      int m = tid >> 4, k = tid & 15;
      Ab[lvl * 16 + m][lvl * 16 + k] = 0;
      Mpad[m][k] = Tb[lvl * 16 + m][lvl * 16 + k];
    }
    __syncthreads();
    f32x4 accP = {};
    #pragma unroll
    for (int ks2 = 0; ks2 < 2; ks2++) {
      bf16x8 a  = *(const bf16x8*)&Ab[lvl * 16 + lrow][ks2 * 32 + lq * 8];
      bf16x8 b2 = *(const bf16x8*)&TbT[wave * 16 + lrow][ks2 * 32 + lq * 8];
      accP = __builtin_amdgcn_mfma_f32_16x16x32_bf16(a, b2, accP, 0, 0, 0);
    }
    {
      int col = wave * 16 + lrow;
      u16x4 qp;
      #pragma unroll
      for (int r = 0; r < 4; r++) {
        int krow = lq * 4 + r;
        float e = (col == lvl * 16 + krow) ? 1.f : 0.f;
        ((unsigned short*)&qp)[r] = f2bf(e - accP[r]);
      }
      *(u16x4*)&Qt[col][lq * 4] = qp;
    }
    __syncthreads();
    {
      bf16x8 am = *(const bf16x8*)&Mpad[lrow][lq * 8];
      bf16x8 bq = *(const bf16x8*)&Qt[wave * 16 + lrow][lq * 8];
      f32x4 accR = {};
      accR = __builtin_amdgcn_mfma_f32_16x16x32_bf16(am, bq, accR, 0, 0, 0);
      #pragma unroll
      for (int r = 0; r < 4; r++) {
        int row = lvl * 16 + lq * 4 + r, col = wave * 16 + lrow;
        unsigned short bv = f2bf(accR[r]);
        Tb[row][col]  = bv;
        TbT[col][row] = bv;
      }
    }
    __syncthreads();
  }
  bf16x8 af0 = *(const bf16x8*)&Tb[wave * 16 + lrow][lq * 8];
  bf16x8 af1 = *(const bf16x8*)&Tb[wave * 16 + lrow][32 + lq * 8];
  #pragma unroll
  for (int nt = 0; nt < 12; nt++) {
    f32x4 acc = {};
    bf16x8 b0 = *(const bf16x8*)&RHSt[nt * 16 + lrow][lq * 8];
    bf16x8 b1 = *(const bf16x8*)&RHSt[nt * 16 + lrow][32 + lq * 8];
    acc = __builtin_amdgcn_mfma_f32_16x16x32_bf16(af0, b0, acc, 0, 0, 0);
    acc = __builtin_amdgcn_mfma_f32_16x16x32_bf16(af1, b1, acc, 0, 0, 0);
    #pragma unroll
    for (int r = 0; r < 4; r++) {
      int i = wave * 16 + lq * 4 + r;
      int col = nt * 16 + lrow;
      if (nt < 8) U0g[(size_t)cid * 8192 + i * 128 + col] = f2bf(acc[r]);
      else        Wmg[(size_t)cid * 4096 + i * 64 + (col - 128)] = f2bf(acc[r]);
    }
  }
}

// ---------- Phase 2: inter-chunk state recurrence, v-split (192 blocks) ----------
__global__ __launch_bounds__(256) void phase2_kernel(
    const unsigned short* __restrict__ kb,
    const unsigned short* __restrict__ U0g, const unsigned short* __restrict__ Wmg,
    const float* __restrict__ Gamg, unsigned short* __restrict__ P0g) {
  int blk = blockIdx.x;              // bh*4 + vc
  int vc = blk & 3, bh = blk >> 2;
  int h = bh % NHh, b = bh / NHh;
  __shared__ __align__(16) unsigned short P_bf[32][72];    // S0 slice [v][d]
  __shared__ __align__(16) unsigned short Wm_lds[64][72];  // [j][d]
  __shared__ __align__(16) unsigned short Ktmp[64][72];    // [j][d]
  __shared__ __align__(16) unsigned short KpT_lds[64][72]; // [d][j]
  __shared__ __align__(16) unsigned short U0_lds[64][40];  // [j][v32]
  __shared__ __align__(16) unsigned short UT_lds[32][72];  // [v][j]
  __shared__ float G2[64];
  int tid = threadIdx.x;
  int wave = tid >> 6, lane = tid & 63, lq = lane >> 4, lrow = lane & 15;
  int vt = wave & 1, dbase = (wave >> 1) * 2;
  f32x4 P[2] = {};
  int pj = tid >> 2, px = (tid & 3) << 4;   // Wm/K: 32B per thread
  int pv = (tid & 3) << 3;                  // U0: 16B per thread (8 shorts)
  ui4 pf_wm0, pf_wm1, pf_k0, pf_k1, pf_u0;
  float pf_g = 0.f;
  {
    size_t cid0 = (size_t)bh * NC;
    int bl0 = b * L_;
    pf_wm0 = *(const ui4*)&Wmg[cid0 * 4096 + pj * 64 + px];
    pf_wm1 = *(const ui4*)&Wmg[cid0 * 4096 + pj * 64 + px + 8];
    pf_k0  = *(const ui4*)&kb[(size_t)(bl0 + pj) * KD + h * 64 + px];
    pf_k1  = *(const ui4*)&kb[(size_t)(bl0 + pj) * KD + h * 64 + px + 8];
    pf_u0  = *(const ui4*)&U0g[cid0 * 8192 + pj * 128 + vc * 32 + pv];
    if (tid < 64) pf_g = Gamg[cid0 * 64 + tid];
  }
  for (int c = 0; c < NC; c++) {
    size_t cid = (size_t)bh * NC + c;
    #pragma unroll
    for (int di = 0; di < 2; di++)
      #pragma unroll
      for (int r = 0; r < 4; r++)
        P_bf[vt * 16 + lq * 4 + r][(dbase + di) * 16 + lrow] = f2bf(P[di][r]);
    *(ui4*)&Wm_lds[pj][px]     = pf_wm0;
    *(ui4*)&Wm_lds[pj][px + 8] = pf_wm1;
    *(ui4*)&Ktmp[pj][px]       = pf_k0;
    *(ui4*)&Ktmp[pj][px + 8]   = pf_k1;
    *(ui4*)&U0_lds[pj][pv]     = pf_u0;
    if (tid < 64) G2[tid] = pf_g;
    __syncthreads();
    float gend = __expf(G2[63]);
    {
      int v = tid >> 3, d8 = (tid & 7) << 3;
      *(ui4*)&P0g[cid * 8192 + (size_t)(vc * 32 + v) * 64 + d8] = *(const ui4*)&P_bf[v][d8];
    }
    if (c + 1 < NC) {
      size_t cid1 = cid + 1;
      int bl1 = b * L_ + ((c + 1) << 6);
      pf_wm0 = *(const ui4*)&Wmg[cid1 * 4096 + pj * 64 + px];
      pf_wm1 = *(const ui4*)&Wmg[cid1 * 4096 + pj * 64 + px + 8];
      pf_k0  = *(const ui4*)&kb[(size_t)(bl1 + pj) * KD + h * 64 + px];
      pf_k1  = *(const ui4*)&kb[(size_t)(bl1 + pj) * KD + h * 64 + px + 8];
      pf_u0  = *(const ui4*)&U0g[cid1 * 8192 + pj * 128 + vc * 32 + pv];
      if (tid < 64) pf_g = Gamg[cid1 * 64 + tid];
    }
    {
      int d = tid & 63, j0 = (tid >> 6) << 4;
      float Ge = G2[63];
      #pragma unroll
      for (int i = 0; i < 16; i++) {
        int j = j0 + i;
        KpT_lds[d][j] = f2bf(__expf(Ge - G2[j]) * bf2f(Ktmp[j][d]));
      }
    }
    #pragma unroll
    for (int vt2 = 0; vt2 < 2; vt2++) {
      f32x4 acc = {};
      #pragma unroll
      for (int ks2 = 0; ks2 < 2; ks2++) {
        bf16x8 a  = *(const bf16x8*)&Wm_lds[wave * 16 + lrow][ks2 * 32 + lq * 8];
        bf16x8 b2 = *(const bf16x8*)&P_bf[vt2 * 16 + lrow][ks2 * 32 + lq * 8];
        acc = __builtin_amdgcn_mfma_f32_16x16x32_bf16(a, b2, acc, 0, 0, 0);
      }
      u16x4 p;
      #pragma unroll
      for (int r = 0; r < 4; r++) {
        int j = wave * 16 + lq * 4 + r;
        ((unsigned short*)&p)[r] = f2bf(bf2f(U0_lds[j][vt2 * 16 + lrow]) - acc[r]);
      }
      *(u16x4*)&UT_lds[vt2 * 16 + lrow][wave * 16 + lq * 4] = p;
    }
    __syncthreads();
    #pragma unroll
    for (int di = 0; di < 2; di++) {
      f32x4 acc = P[di];
      #pragma unroll
      for (int r = 0; r < 4; r++) acc[r] *= gend;
      #pragma unroll
      for (int ks2 = 0; ks2 < 2; ks2++) {
        bf16x8 a  = *(const bf16x8*)&UT_lds[vt * 16 + lrow][ks2 * 32 + lq * 8];
        bf16x8 b2 = *(const bf16x8*)&KpT_lds[(dbase + di) * 16 + lrow][ks2 * 32 + lq * 8];
        acc = __builtin_amdgcn_mfma_f32_16x16x32_bf16(a, b2, acc, 0, 0, 0);
      }
      P[di] = acc;
    }
  }
}

// ---------- Phase 3: per-chunk output (parallel, 1536 blocks) ----------
__global__ __launch_bounds__(256) void phase3_kernel(
    const unsigned short* __restrict__ qb, const unsigned short* __restrict__ kb,
    const unsigned short* __restrict__ U0g, const unsigned short* __restrict__ Wmg,
    const unsigned short* __restrict__ P0g, const float* __restrict__ Gamg,
    unsigned short* __restrict__ o_raw) {
  int cid = blockIdx.x;
  int c = cid & (NC - 1), bh = cid >> 5;
  int h = bh % NHh, b = bh / NHh;
  int bl0 = b * L_ + (c << 6);
  __shared__ __align__(16) unsigned short Q_lds[64][72];
  __shared__ __align__(16) unsigned short K_lds[64][72];
  __shared__ __align__(16) unsigned short WM_lds[64][72];
  __shared__ __align__(16) unsigned short P0_lds[128][72];
  __shared__ __align__(16) unsigned short U0_lds[64][128];
  __shared__ __align__(16) unsigned short UT_lds[128][72];
  __shared__ float G_lds[64];
  int tid = threadIdx.x;
  int wave = tid >> 6, lane = tid & 63, lq = lane >> 4, lrow = lane & 15;
  {
    int j = tid >> 2, d0 = (tid & 3) << 4;
    const ui4* qs = (const ui4*)&qb[(size_t)(bl0 + j) * KD + h * 64 + d0];
    *(ui4*)&Q_lds[j][d0] = qs[0];  *(ui4*)&Q_lds[j][d0 + 8] = qs[1];
    const ui4* ks = (const ui4*)&kb[(size_t)(bl0 + j) * KD + h * 64 + d0];
    *(ui4*)&K_lds[j][d0] = ks[0];  *(ui4*)&K_lds[j][d0 + 8] = ks[1];
    const ui4* ws = (const ui4*)&Wmg[(size_t)cid * 4096 + j * 64 + d0];
    *(ui4*)&WM_lds[j][d0] = ws[0]; *(ui4*)&WM_lds[j][d0 + 8] = ws[1];
    int v = tid >> 1, e0 = (tid & 1) << 5;
    const ui4* ps = (const ui4*)&P0g[(size_t)cid * 8192 + v * 64 + e0];
    *(ui4*)&P0_lds[v][e0]      = ps[0]; *(ui4*)&P0_lds[v][e0 + 8]  = ps[1];
    *(ui4*)&P0_lds[v][e0 + 16] = ps[2]; *(ui4*)&P0_lds[v][e0 + 24] = ps[3];
    int e1 = tid * 32;
    const ui4* us = (const ui4*)&U0g[(size_t)cid * 8192 + e1];
    ui4* ud = (ui4*)&U0_lds[0][e1];
    ud[0] = us[0]; ud[1] = us[1]; ud[2] = us[2]; ud[3] = us[3];
    if (tid < 64) G_lds[tid] = Gamg[(size_t)cid * 64 + tid];
  }
  __syncthreads();
  #pragma unroll
  for (int nt = 0; nt < 8; nt++) {
    f32x4 acc = {};
    #pragma unroll
    for (int ks2 = 0; ks2 < 2; ks2++) {
      bf16x8 a  = *(const bf16x8*)&WM_lds[wave * 16 + lrow][ks2 * 32 + lq * 8];
      bf16x8 b2 = *(const bf16x8*)&P0_lds[nt * 16 + lrow][ks2 * 32 + lq * 8];
      acc = __builtin_amdgcn_mfma_f32_16x16x32_bf16(a, b2, acc, 0, 0, 0);
    }
    u16x4 p;
    #pragma unroll
    for (int r = 0; r < 4; r++) {
      int j = wave * 16 + lq * 4 + r;
      ((unsigned short*)&p)[r] = f2bf(bf2f(U0_lds[j][nt * 16 + lrow]) - acc[r]);
    }
    *(u16x4*)&UT_lds[nt * 16 + lrow][wave * 16 + lq * 4] = p;
  }
  __syncthreads();
  #pragma unroll
  for (int mt = 0; mt < 4; mt++) {
    f32x4 acc = {};
    #pragma unroll
    for (int ks2 = 0; ks2 < 2; ks2++) {
      bf16x8 a  = *(const bf16x8*)&Q_lds[wave * 16 + lrow][ks2 * 32 + lq * 8];
      bf16x8 b2 = *(const bf16x8*)&K_lds[mt * 16 + lrow][ks2 * 32 + lq * 8];
      acc = __builtin_amdgcn_mfma_f32_16x16x32_bf16(a, b2, acc, 0, 0, 0);
    }
    #pragma unroll
    for (int r = 0; r < 4; r++) {
      int i = wave * 16 + lq * 4 + r, j = mt * 16 + lrow;
      WM_lds[i][j] = (j <= i) ? f2bf(__expf(G_lds[i] - G_lds[j]) * acc[r]) : (unsigned short)0;
    }
  }
  __syncthreads();
  #pragma unroll
  for (int nt = 0; nt < 8; nt++) {
    f32x4 accO = {}, accS = {};
    #pragma unroll
    for (int ks2 = 0; ks2 < 2; ks2++) {
      bf16x8 aM = *(const bf16x8*)&WM_lds[wave * 16 + lrow][ks2 * 32 + lq * 8];
      bf16x8 bU = *(const bf16x8*)&UT_lds[nt * 16 + lrow][ks2 * 32 + lq * 8];
      accO = __builtin_amdgcn_mfma_f32_16x16x32_bf16(aM, bU, accO, 0, 0, 0);
      bf16x8 aQ = *(const bf16x8*)&Q_lds[wave * 16 + lrow][ks2 * 32 + lq * 8];
      bf16x8 bP = *(const bf16x8*)&P0_lds[nt * 16 + lrow][ks2 * 32 + lq * 8];
      accS = __builtin_amdgcn_mfma_f32_16x16x32_bf16(aQ, bP, accS, 0, 0, 0);
    }
    #pragma unroll
    for (int r = 0; r < 4; r++) {
      int i = wave * 16 + lq * 4 + r;
      float o = accO[r] + __expf(G_lds[i]) * accS[r];
      o_raw[(size_t)(bl0 + i) * VD + h * 128 + nt * 16 + lrow] = f2bf(o);
    }
  }
}

// ---------- rmsnorm + gnorm_w * silu(g), in-place on o_raw ----------
__global__ void norm_gate_kernel(unsigned short* __restrict__ o_raw,
                                 const unsigned short* __restrict__ g,
                                 const float* __restrict__ gnw) {
  int tid = threadIdx.x;
  int r = blockIdx.x * 16 + (tid >> 4);
  int v = (tid & 15) * 8;
  u16x8 xo = *(const u16x8*)&o_raw[(size_t)r * DVh + v];
  u16x8 xg = *(const u16x8*)&g[(size_t)r * DVh + v];
  float x[8], ss = 0.f;
  #pragma unroll
  for (int e = 0; e < 8; e++) {
    x[e] = bf2f(xo[e]);
    ss += x[e] * x[e];
  }
  #pragma unroll
  for (int off = 1; off <= 8; off <<= 1) ss += __shfl_xor(ss, off);
  float inv = rsqrtf(ss * (1.f / (float)DVh) + 1e-5f);
  f4v w0 = *(const f4v*)&gnw[v];
  f4v w1 = *(const f4v*)&gnw[v + 4];
  u16x8 o;
  #pragma unroll
  for (int e = 0; e < 8; e++) {
    float gv = bf2f(xg[e]);
    float wv = (e < 4) ? w0[e] : w1[e - 4];
    o[e] = f2bf(x[e] * inv * wv * (gv * sigmoidf_(gv)));
  }
  *(u16x8*)&o_raw[(size_t)r * DVh + v] = o;
}

// ---------- host launch ----------
extern "C" void kernel_launch(void* const* d_in, const int* in_sizes, int n_in,
                              void* d_out, int out_size, void* d_ws, size_t ws_size,
                              hipStream_t stream) {
  const void* hs      = d_in[0];
  const void* Wq      = d_in[1];
  const void* Wk      = d_in[2];
  const void* Wv      = d_in[3];
  const void* Wg      = d_in[4];
  const void* Wgk     = d_in[5];
  const void* Wb      = d_in[6];
  const void* bb      = d_in[7];
  const void* cq      = d_in[8];
  const void* ck      = d_in[9];
  const void* cv      = d_in[10];
  const void* A_log   = d_in[11];
  const void* gnorm_w = d_in[12];
  const void* Wo      = d_in[13];
  const void* dt_bias = d_in[14];

  char* wsB = (char*)d_ws;
  size_t off = 0;
  auto walloc = [&](size_t bytes) -> char* {
    char* p = wsB + off;
    off += (bytes + 1023) & ~(size_t)1023;
    return p;
  };
  int* flag = (int*)walloc(1024);
  // NOTE: WqT..WgT must stay contiguous (fused BT of [4608][1024]); all sizes
  // are multiples of 1024 so walloc adds no padding between them.
  unsigned short* WqT   = (unsigned short*)walloc((size_t)KD * H_ * 2);
  unsigned short* WkT   = (unsigned short*)walloc((size_t)KD * H_ * 2);
  unsigned short* WvT   = (unsigned short*)walloc((size_t)VD * H_ * 2);
  unsigned short* WgT   = (unsigned short*)walloc((size_t)VD * H_ * 2);
  unsigned short* WgkbT = (unsigned short*)walloc((size_t)128 * H_ * 2);
  unsigned short* WoT   = (unsigned short*)walloc((size_t)H_ * VD * 2);
  float* cqf   = (float*)walloc((size_t)KD * 4 * 4);
  float* ckf   = (float*)walloc((size_t)KD * 4 * 4);
  float* cvf   = (float*)walloc((size_t)VD * 4 * 4);
  float* bbf   = (float*)walloc(NHh * 4);
  float* A_logf= (float*)walloc(NHh * 4);
  float* dtf   = (float*)walloc(NHh * 4);
  float* gnwf  = (float*)walloc(DVh * 4);
  float* gkb   = (float*)walloc((size_t)M_ * NHh * 4);
  float* betab = (float*)walloc((size_t)M_ * NHh * 4);
  float* Gamg  = (float*)walloc((size_t)NCID * 64 * 4);
  unsigned short* c_hs  = (unsigned short*)walloc((size_t)M_ * H_ * 2);
  // qkraw/vraw/gbuf must stay contiguous (fused GEMM C routing).
  unsigned short* qkraw = (unsigned short*)walloc((size_t)M_ * 1536 * 2);
  unsigned short* vraw  = (unsigned short*)walloc((size_t)M_ * VD * 2);
  unsigned short* gbuf  = (unsigned short*)walloc((size_t)M_ * VD * 2);
  unsigned short* qb    = (unsigned short*)walloc((size_t)M_ * KD * 2);
  unsigned short* kb    = (unsigned short*)walloc((size_t)M_ * KD * 2);
  unsigned short* vb    = (unsigned short*)walloc((size_t)M_ * VD * 2);
  // overlays (safe by launch order):
  float*          logits32 = (float*)vraw;   // consumed by gkbeta BEFORE fused GEMM
  unsigned short* Wmg   = c_hs;
  unsigned short* U0g   = qkraw;
  unsigned short* o_raw = vraw;
  unsigned short* P0g   = vb;

  // 0. dtype detection + canonicalization
  detect_dtype<<<1, 256, 0, stream>>>((const unsigned short*)hs, flag);
  convert_small<<<dim3(24, 7), 256, 0, stream>>>(cq, ck, cv, bb, A_log, dt_bias, gnorm_w,
                                                 cqf, ckf, cvf, bbf, A_logf, dtf, gnwf, flag);
  transpose_conv<<<dim3(KD / 32, H_ / 32), 256, 0, stream>>>(Wq, WqT, H_, KD, flag);
  transpose_conv<<<dim3(KD / 32, H_ / 32), 256, 0, stream>>>(Wk, WkT, H_, KD, flag);
  transpose_conv<<<dim3(VD / 32, H_ / 32), 256, 0, stream>>>(Wv, WvT, H_, VD, flag);
  transpose_conv<<<dim3(VD / 32, H_ / 32), 256, 0, stream>>>(Wg, WgT, H_, VD, flag);
  transpose_conv<<<dim3(1, H_ / 32), 256, 0, stream>>>(Wgk, WgkbT, H_, NHh, flag);
  transpose_conv<<<dim3(1, H_ / 32), 256, 0, stream>>>(Wb, WgkbT + 12 * H_, H_, NHh, flag);
  transpose_conv<<<dim3(H_ / 32, VD / 32), 256, 0, stream>>>(Wo, WoT, VD, H_, flag);
  convert_hs4<<<(M_ * H_) / 1024, 256, 0, stream>>>(hs, c_hs, flag);

  // 1a. gk/beta logits first (logits32 overlays vraw; consume before fused GEMM)
  gemm_bt<<<dim3(M_ / 128, 1), 256, 0, stream>>>(c_hs, WgkbT, logits32, M_, 128, H_, 1, flag);
  gkbeta_kernel<<<(M_ * 24) / 256, 256, 0, stream>>>(logits32, bbf, A_logf, dtf, gkb, betab);
  // 1b. fused q|k|v|g projection: BT = [WqT;WkT;WvT;WgT] = [4608][1024],
  //     C routed per 128-col tile into qkraw / vraw / gbuf (mode 3)
  gemm_bt<<<dim3(M_ / 128, 4608 / 128), 256, 0, stream>>>(c_hs, WqT, qkraw, M_, 4608, H_, 3, flag);

  // 2. conv + silu (+ l2norm for q/k) — vectorized 16B/lane
  conv_qk_kernel<<<M_ / 2, 192, 0, stream>>>(qkraw, 1536, cqf, qb);
  conv_qk_kernel<<<M_ / 2, 192, 0, stream>>>(qkraw + KD, 1536, ckf, kb);
  conv_v_kernel<<<(M_ * 192) / 256, 256, 0, stream>>>(vraw, cvf, vb);

  // 3. chunked gated delta rule
  phase1_kernel<<<NCID, 256, 0, stream>>>(kb, vb, gkb, betab, U0g, Wmg, Gamg);
  phase2_kernel<<<B_ * NHh * 4, 256, 0, stream>>>(kb, U0g, Wmg, Gamg, P0g);
  phase3_kernel<<<NCID, 256, 0, stream>>>(qb, kb, U0g, Wmg, P0g, Gamg, o_raw);

  // 4. rmsnorm + swish gate (in-place on o_raw) — vectorized
  norm_gate_kernel<<<(M_ * NHh) / 16, 256, 0, stream>>>(o_raw, gbuf, gnwf);

  // 5. output projection (dtype-flag-selected store)
  gemm_bt<<<dim3(M_ / 128, H_ / 128), 256, 0, stream>>>(o_raw, WoT, d_out, M_, H_, VD, 2, flag);
}

// Round 6
// 446.217 us; speedup vs baseline: 1.0717x; 1.0250x over previous
//
#include <hip/hip_runtime.h>

// ---------- problem constants ----------
#define B_   4
#define L_   2048
#define H_   1024
#define KD   768
#define VD   1536
#define NHh  12
#define DKh  64
#define DVh  128
#define M_   (B_ * L_)   // 8192 rows
#define NC   32          // chunks per sequence (L/64)
#define NCID (B_ * NHh * NC)  // 1536

using bf16x8 = __attribute__((ext_vector_type(8))) __bf16;
using f32x4  = __attribute__((ext_vector_type(4))) float;
using ui4    = __attribute__((ext_vector_type(4))) unsigned int;
using f4v    = __attribute__((ext_vector_type(4))) float;
using u16x4  = __attribute__((ext_vector_type(4))) unsigned short;
using u16x8  = __attribute__((ext_vector_type(8))) unsigned short;

__device__ __forceinline__ float bf2f(unsigned short u) {
  unsigned int x = ((unsigned int)u) << 16;
  return __builtin_bit_cast(float, x);
}
__device__ __forceinline__ unsigned short f2bf(float f) {
  unsigned int u = __builtin_bit_cast(unsigned int, f);
  u += 0x7fffu + ((u >> 16) & 1u);
  return (unsigned short)(u >> 16);
}
__device__ __forceinline__ float sigmoidf_(float x) { return 1.f / (1.f + __expf(-x)); }

// async global->LDS DMA, 16B per lane; lds dest must be wave-uniform base (+lane*16 implicit)
__device__ __forceinline__ void async_copy16(const unsigned short* __restrict__ g,
                                             unsigned short* l) {
  __builtin_amdgcn_global_load_lds((const __attribute__((address_space(1))) unsigned int*)g,
                                   (__attribute__((address_space(3))) unsigned int*)l, 16, 0, 0);
}

// ---------- dtype detector: flag=1 if inputs are fp32, 0 if bf16 ----------
__global__ void detect_dtype(const unsigned short* __restrict__ hs, int* __restrict__ flag) {
  int tid = threadIdx.x;  // 256 threads
  int cnt = 0;
  for (int i = tid; i < 1024; i += 256) {
    int e = (hs[i] >> 7) & 0xFF;
    if (e >= 134) cnt++;
  }
  #pragma unroll
  for (int off = 32; off; off >>= 1) cnt += __shfl_xor(cnt, off);
  __shared__ int red[4];
  if ((tid & 63) == 0) red[tid >> 6] = cnt;
  __syncthreads();
  if (tid == 0) *flag = (red[0] + red[1] + red[2] + red[3] > 100) ? 1 : 0;
}

// ---------- convert hidden_states -> canonical bf16 ----------
__global__ void convert_hs4(const void* __restrict__ src, unsigned short* __restrict__ dst,
                            const int* __restrict__ flag) {
  size_t i = ((size_t)blockIdx.x * 256 + threadIdx.x) * 4;
  if (*flag) {
    f4v v = *(const f4v*)((const float*)src + i);
    u16x4 o;
    o.x = f2bf(v[0]); o.y = f2bf(v[1]); o.z = f2bf(v[2]); o.w = f2bf(v[3]);
    *(u16x4*)(dst + i) = o;
  } else {
    *(u16x4*)(dst + i) = *(const u16x4*)((const unsigned short*)src + i);
  }
}

// ---------- convert 7 small arrays -> canonical fp32 ----------
// conv weights (a=0,1,2) are additionally TRANSPOSED: in [C][4] -> out [4][C]
__global__ void convert_small(const void* s0, const void* s1, const void* s2,
                              const void* s3, const void* s4, const void* s5, const void* s6,
                              float* d0, float* d1, float* d2, float* d3, float* d4,
                              float* d5, float* d6, const int* __restrict__ flag) {
  const int sizes[7] = {KD * 4, KD * 4, VD * 4, NHh, NHh, NHh, DVh};
  int a = blockIdx.y;
  const void* s; float* d;
  switch (a) {
    case 0: s = s0; d = d0; break;  case 1: s = s1; d = d1; break;
    case 2: s = s2; d = d2; break;  case 3: s = s3; d = d3; break;
    case 4: s = s4; d = d4; break;  case 5: s = s5; d = d5; break;
    default: s = s6; d = d6; break;
  }
  int i = blockIdx.x * 256 + threadIdx.x;
  if (i >= sizes[a]) return;
  float v = (*flag) ? ((const float*)s)[i] : bf2f(((const unsigned short*)s)[i]);
  if (a < 3) {
    int C = (a == 2) ? VD : KD;
    d[(i & 3) * C + (i >> 2)] = v;   // transposed [j][c]
  } else {
    d[i] = v;
  }
}

// ---------- weight transpose+convert: in [R][C] (flag dtype) -> out bf16 [C][R] ----------
__global__ void transpose_conv(const void* __restrict__ in, unsigned short* __restrict__ out,
                               int R, int C, const int* __restrict__ flag) {
  __shared__ unsigned short tile[32][33];
  int f = *flag;
  int c0 = blockIdx.x * 32, r0 = blockIdx.y * 32;
  int tx = threadIdx.x & 31, ty = threadIdx.x >> 5;
  #pragma unroll
  for (int i = 0; i < 32; i += 8) {
    int r = r0 + ty + i, c = c0 + tx;
    unsigned short v = 0;
    if (r < R && c < C)
      v = f ? f2bf(((const float*)in)[(size_t)r * C + c])
            : ((const unsigned short*)in)[(size_t)r * C + c];
    tile[ty + i][tx] = v;
  }
  __syncthreads();
  #pragma unroll
  for (int i = 0; i < 32; i += 8) {
    int c = c0 + ty + i, r = r0 + tx;
    if (c < C && r < R) out[(size_t)c * R + r] = tile[tx][ty + i];
  }
}

// ---------- MFMA GEMM: C[M,N] = A[M,K] * B[K,N], BT = B^T [N,K] ----------
// Round 6: same 128^2 tile / 64KB dbuf LDS / counted vmcnt (verified R5),
// but 512 threads (8 waves, 2x4 grid, acc[4][2]/wave). LDS still limits to
// 2 blocks/CU, so waves/SIMD doubles 2->4 — more TLP to hide the drain.
// Per-thread loads/stage = 4 (2A+2B), so counted drain = vmcnt(4).
// Per iter: vmcnt(4) -> barrier -> compute(buf t) -> barrier -> stage(t+2).
// f32mode: 0=bf16, 1=f32, 2=flag-selected, 3=fused q|k|v|g routing (1536-col regions).
#define BMt 128
#define BNt 128
#define BKt 64

__global__ __launch_bounds__(512, 4) void gemm_bt(
    const unsigned short* __restrict__ Ag,
    const unsigned short* __restrict__ BTg,
    void* __restrict__ Cg,
    int M, int N, int K, int f32mode, const int* __restrict__ flag) {
  __shared__ __align__(16) unsigned short As[2][BMt * BKt];
  __shared__ __align__(16) unsigned short Bs[2][BNt * BKt];
  const int tid = threadIdx.x;
  const int wave = tid >> 6, lane = tid & 63;
  const int wr = wave >> 2, wc = wave & 3;   // 2 x 4 wave grid: 64-row x 32-col per wave
  const int lrow = lane & 15, lq = lane >> 4;
  const int row0 = blockIdx.x * BMt;
  const int bcol0 = blockIdx.y * BNt;
  // C routing
  unsigned short* Cb = (unsigned short*)Cg;
  int col0 = bcol0, Nst = N;
  if (f32mode == 3) {
    int region = bcol0 / 1536;
    Cb += (size_t)region * (size_t)M_ * 1536;
    col0 = bcol0 - region * 1536;
    Nst = 1536;
  }
  f32x4 acc[4][2] = {};
  // staging: chunk c in [0,1024): r=c>>3, LDS slot u=c&7 holds global slot u^(r&7)
  auto stage = [&](int sb, int k0) {
    #pragma unroll
    for (int i = 0; i < 2; i++) {
      int c = i * 512 + tid;
      int r = c >> 3;
      int kk = ((c & 7) ^ (r & 7)) << 3;   // pre-swizzled source slot
      int ldsbase = (i * 512 + wave * 64) * 8;   // wave-uniform elem offset
      async_copy16(&Ag[(size_t)(row0 + r) * K + k0 + kk], &As[sb][ldsbase]);
      async_copy16(&BTg[(size_t)(bcol0 + r) * K + k0 + kk], &Bs[sb][ldsbase]);
    }
  };
  const int NT = K / BKt;
  stage(0, 0);
  if (NT > 1) stage(1, BKt);
  for (int t = 0; t < NT; t++) {
    // Drain only tile t's 4 loads (per-wave oldest); tile t+1's stay in flight.
    if (t + 1 < NT) asm volatile("s_waitcnt vmcnt(4)" ::: "memory");
    else            asm volatile("s_waitcnt vmcnt(0)" ::: "memory");
    __builtin_amdgcn_s_barrier();       // all waves' tile-t loads are in LDS
    const int cur = t & 1;
    #pragma unroll
    for (int ks = 0; ks < BKt; ks += 32) {
      bf16x8 af[4], bfr[2];
      #pragma unroll
      for (int i = 0; i < 4; i++) {
        int ra = wr * 64 + i * 16 + lrow;
        int sa = ((ks >> 3) + lq) ^ (ra & 7);
        af[i]  = *(const bf16x8*)&As[cur][ra * BKt + (sa << 3)];
      }
      #pragma unroll
      for (int i = 0; i < 2; i++) {
        int rb = wc * 32 + i * 16 + lrow;
        int sb2 = ((ks >> 3) + lq) ^ (rb & 7);
        bfr[i] = *(const bf16x8*)&Bs[cur][rb * BKt + (sb2 << 3)];
      }
      __builtin_amdgcn_s_setprio(1);
      #pragma unroll
      for (int mi = 0; mi < 4; mi++)
        #pragma unroll
        for (int ni = 0; ni < 2; ni++)
          acc[mi][ni] = __builtin_amdgcn_mfma_f32_16x16x32_bf16(af[mi], bfr[ni], acc[mi][ni], 0, 0, 0);
      __builtin_amdgcn_s_setprio(0);
    }
    __builtin_amdgcn_s_barrier();       // all waves done reading buffer cur
    if (t + 2 < NT) stage(cur, (t + 2) * BKt);   // buffer released by barrier
  }
  bool f32 = (f32mode == 1) || (f32mode == 2 && *flag != 0);
  #pragma unroll
  for (int mi = 0; mi < 4; mi++)
    #pragma unroll
    for (int ni = 0; ni < 2; ni++)
      #pragma unroll
      for (int r = 0; r < 4; r++) {
        int rr = row0 + wr * 64 + mi * 16 + lq * 4 + r;
        int cc = col0 + wc * 32 + ni * 16 + lrow;
        float v = acc[mi][ni][r];
        if (f32) ((float*)Cg)[(size_t)rr * N + cc] = v;
        else     Cb[(size_t)rr * Nst + cc] = f2bf(v);
      }
}

// ---------- gk/beta from fp32 logits [M][128] (cols 0..11 gk, 12..23 beta) ----------
__global__ void gkbeta_kernel(const float* __restrict__ logits,
                              const float* __restrict__ bb,
                              const float* __restrict__ A_log,
                              const float* __restrict__ dt_bias,
                              float* __restrict__ gkb, float* __restrict__ betab) {
  int idx = blockIdx.x * 256 + threadIdx.x;   // m*24 + j
  int m = idx / 24, j = idx - m * 24;
  float x = logits[(size_t)m * 128 + j];
  if (j < 12) {
    float t = x + dt_bias[j];
    float sp = (t > 20.f) ? t : log1pf(__expf(t));
    gkb[m * NHh + j] = -__expf(A_log[j]) * sp;
  } else {
    betab[m * NHh + (j - 12)] = sigmoidf_(x + bb[j - 12]);
  }
}

// ---------- causal dwconv(K=4) + silu + per-head l2norm (q/k, strided src) ----------
__global__ __launch_bounds__(192) void conv_qk_kernel(
    const unsigned short* __restrict__ raw, int rstride,
    const float* __restrict__ w,
    unsigned short* __restrict__ outp) {
  int tid = threadIdx.x;
  int rib = tid / 96, within = tid - rib * 96;   // row-in-block, 0..95
  int bl = blockIdx.x * 2 + rib;
  int c = within * 8;                             // channel base 0..760
  int l = bl & (L_ - 1);
  float acc[8] = {};
  #pragma unroll
  for (int j = 0; j < 4; j++) {
    int ll = l - 3 + j;
    if (ll >= 0) {
      u16x8 v = *(const u16x8*)&raw[(size_t)(bl - 3 + j) * rstride + c];
      f4v w0 = *(const f4v*)&w[j * KD + c];
      f4v w1 = *(const f4v*)&w[j * KD + c + 4];
      #pragma unroll
      for (int e = 0; e < 4; e++) acc[e] += bf2f(v[e]) * w0[e];
      #pragma unroll
      for (int e = 0; e < 4; e++) acc[4 + e] += bf2f(v[4 + e]) * w1[e];
    }
  }
  float x[8], ss = 0.f;
  #pragma unroll
  for (int e = 0; e < 8; e++) {
    float a = acc[e];
    x[e] = a * sigmoidf_(a);
    ss += x[e] * x[e];
  }
  #pragma unroll
  for (int off = 1; off <= 4; off <<= 1) ss += __shfl_xor(ss, off);
  float inv = 1.f / fmaxf(sqrtf(ss), 1e-12f);
  u16x8 o;
  #pragma unroll
  for (int e = 0; e < 8; e++) o[e] = f2bf(x[e] * inv);
  *(u16x8*)&outp[(size_t)bl * KD + c] = o;
}

// ---------- causal dwconv(K=4) + silu for v ----------
__global__ void conv_v_kernel(const unsigned short* __restrict__ raw,
                              const float* __restrict__ w,
                              unsigned short* __restrict__ outp) {
  int idx = blockIdx.x * 256 + threadIdx.x;   // M_ * 192 tasks
  int bl = idx / 192;
  int c = (idx - bl * 192) * 8;
  int l = bl & (L_ - 1);
  float acc[8] = {};
  #pragma unroll
  for (int j = 0; j < 4; j++) {
    int ll = l - 3 + j;
    if (ll >= 0) {
      u16x8 v = *(const u16x8*)&raw[(size_t)(bl - 3 + j) * VD + c];
      f4v w0 = *(const f4v*)&w[j * VD + c];
      f4v w1 = *(const f4v*)&w[j * VD + c + 4];
      #pragma unroll
      for (int e = 0; e < 4; e++) acc[e] += bf2f(v[e]) * w0[e];
      #pragma unroll
      for (int e = 0; e < 4; e++) acc[4 + e] += bf2f(v[4 + e]) * w1[e];
    }
  }
  u16x8 o;
  #pragma unroll
  for (int e = 0; e < 8; e++) {
    float a = acc[e];
    o[e] = f2bf(a * sigmoidf_(a));
  }
  *(u16x8*)&outp[(size_t)bl * VD + c] = o;
}

// ================= CHUNKED GATED DELTA RULE =================
// ---------- Phase 1: per-chunk precompute (parallel, 1536 blocks) ----------
__global__ __launch_bounds__(256) void phase1_kernel(
    const unsigned short* __restrict__ kb, const unsigned short* __restrict__ vb,
    const float* __restrict__ gkb, const float* __restrict__ betab,
    unsigned short* __restrict__ U0g, unsigned short* __restrict__ Wmg,
    float* __restrict__ Gamg) {
  int cid = blockIdx.x;
  int c = cid & (NC - 1), bh = cid >> 5;
  int h = bh % NHh, b = bh / NHh;
  int bl0 = b * L_ + (c << 6);
  __shared__ __align__(16) unsigned short K_lds[64][72];
  __shared__ __align__(16) unsigned short Ab[64][72];
  __shared__ __align__(16) unsigned short Tb[64][72];
  __shared__ __align__(16) unsigned short TbT[64][72];
  __shared__ __align__(16) unsigned short Qt[64][40];
  __shared__ __align__(16) unsigned short Mpad[16][40];
  __shared__ __align__(16) unsigned short RHSt[192][72];
  __shared__ float G_lds[64], beta_lds[64], besc_lds[64];
  int tid = threadIdx.x;
  int wave = tid >> 6, lane = tid & 63, lq = lane >> 4, lrow = lane & 15;
  {
    u16x4 z = {};
    unsigned short* tb = &Tb[0][0];  unsigned short* tt = &TbT[0][0];
    for (int i = tid * 4; i < 64 * 72; i += 1024) {
      *(u16x4*)&tb[i] = z;  *(u16x4*)&tt[i] = z;
    }
    unsigned short* qt = &Qt[0][0];
    for (int i = tid * 4; i < 64 * 40; i += 1024) *(u16x4*)&qt[i] = z;
    if (tid < 160) *(u16x4*)&(&Mpad[0][0])[tid * 4] = z;
  }
  {
    int j = tid >> 2, d0 = (tid & 3) << 4;
    const ui4* src = (const ui4*)&kb[(size_t)(bl0 + j) * KD + h * 64 + d0];
    *(ui4*)&K_lds[j][d0]     = src[0];
    *(ui4*)&K_lds[j][d0 + 8] = src[1];
  }
  if (tid < 64) {
    float g  = gkb[(size_t)(bl0 + tid) * NHh + h];
    float bt = betab[(size_t)(bl0 + tid) * NHh + h];
    #pragma unroll
    for (int off = 1; off < 64; off <<= 1) {
      int src = lane - off;
      float y = __shfl(g, src < 0 ? 0 : src);
      if (lane >= off) g += y;
    }
    G_lds[tid]    = g;
    beta_lds[tid] = bt;
    besc_lds[tid] = bt * __expf(g);
    Gamg[(size_t)cid * 64 + tid] = g;
  }
  __syncthreads();
  #pragma unroll
  for (int mt = 0; mt < 4; mt++) {
    f32x4 acc = {};
    #pragma unroll
    for (int ks = 0; ks < 2; ks++) {
      bf16x8 a  = *(const bf16x8*)&K_lds[wave * 16 + lrow][ks * 32 + lq * 8];
      bf16x8 b2 = *(const bf16x8*)&K_lds[mt * 16 + lrow][ks * 32 + lq * 8];
      acc = __builtin_amdgcn_mfma_f32_16x16x32_bf16(a, b2, acc, 0, 0, 0);
    }
    #pragma unroll
    for (int r = 0; r < 4; r++) {
      int j = wave * 16 + lq * 4 + r, m = mt * 16 + lrow;
      Ab[j][m] = (m < j) ? f2bf(beta_lds[j] * __expf(G_lds[j] - G_lds[m]) * acc[r])
                         : (unsigned short)0;
    }
  }
  __syncthreads();
  if (wave == 0) {
    int blk = lq, cc = lrow, base = blk * 16;
    float t[16];
    t[0] = (cc == 0) ? 1.f : 0.f;
    #pragma unroll
    for (int j = 1; j < 16; j++) {
      float s = 0.f;
      #pragma unroll
      for (int m = 0; m < j; m++)
        s += bf2f(Ab[base + j][base + m]) * t[m];
      t[j] = ((cc == j) ? 1.f : 0.f) - s;
    }
    #pragma unroll
    for (int j = 0; j < 16; j++) {
      unsigned short bv = f2bf(t[j]);
      Tb[base + j][base + cc]  = bv;
      TbT[base + cc][base + j] = bv;
    }
  } else {
    int r = tid - 64;   // 0..191
    if (r < 128) {
      const unsigned short* vp = &vb[(size_t)bl0 * VD + h * 128 + r];
      for (int j = 0; j < 64; j++)
        RHSt[r][j] = f2bf(beta_lds[j] * bf2f(vp[(size_t)j * VD]));
    } else {
      int d = r - 128;
      for (int j = 0; j < 64; j++)
        RHSt[r][j] = f2bf(besc_lds[j] * bf2f(K_lds[j][d]));
    }
  }
  __syncthreads();
  #pragma unroll
  for (int lvl = 1; lvl < 4; lvl++) {
    {
      int m = tid >> 4, k = tid & 15;
      Ab[lvl * 16 + m][lvl * 16 + k] = 0;
      Mpad[m][k] = Tb[lvl * 16 + m][lvl * 16 + k];
    }
    __syncthreads();
    f32x4 accP = {};
    #pragma unroll
    for (int ks2 = 0; ks2 < 2; ks2++) {
      bf16x8 a  = *(const bf16x8*)&Ab[lvl * 16 + lrow][ks2 * 32 + lq * 8];
      bf16x8 b2 = *(const bf16x8*)&TbT[wave * 16 + lrow][ks2 * 32 + lq * 8];
      accP = __builtin_amdgcn_mfma_f32_16x16x32_bf16(a, b2, accP, 0, 0, 0);
    }
    {
      int col = wave * 16 + lrow;
      u16x4 qp;
      #pragma unroll
      for (int r = 0; r < 4; r++) {
        int krow = lq * 4 + r;
        float e = (col == lvl * 16 + krow) ? 1.f : 0.f;
        ((unsigned short*)&qp)[r] = f2bf(e - accP[r]);
      }
      *(u16x4*)&Qt[col][lq * 4] = qp;
    }
    __syncthreads();
    {
      bf16x8 am = *(const bf16x8*)&Mpad[lrow][lq * 8];
      bf16x8 bq = *(const bf16x8*)&Qt[wave * 16 + lrow][lq * 8];
      f32x4 accR = {};
      accR = __builtin_amdgcn_mfma_f32_16x16x32_bf16(am, bq, accR, 0, 0, 0);
      #pragma unroll
      for (int r = 0; r < 4; r++) {
        int row = lvl * 16 + lq * 4 + r, col = wave * 16 + lrow;
        unsigned short bv = f2bf(accR[r]);
        Tb[row][col]  = bv;
        TbT[col][row] = bv;
      }
    }
    __syncthreads();
  }
  bf16x8 af0 = *(const bf16x8*)&Tb[wave * 16 + lrow][lq * 8];
  bf16x8 af1 = *(const bf16x8*)&Tb[wave * 16 + lrow][32 + lq * 8];
  #pragma unroll
  for (int nt = 0; nt < 12; nt++) {
    f32x4 acc = {};
    bf16x8 b0 = *(const bf16x8*)&RHSt[nt * 16 + lrow][lq * 8];
    bf16x8 b1 = *(const bf16x8*)&RHSt[nt * 16 + lrow][32 + lq * 8];
    acc = __builtin_amdgcn_mfma_f32_16x16x32_bf16(af0, b0, acc, 0, 0, 0);
    acc = __builtin_amdgcn_mfma_f32_16x16x32_bf16(af1, b1, acc, 0, 0, 0);
    #pragma unroll
    for (int r = 0; r < 4; r++) {
      int i = wave * 16 + lq * 4 + r;
      int col = nt * 16 + lrow;
      if (nt < 8) U0g[(size_t)cid * 8192 + i * 128 + col] = f2bf(acc[r]);
      else        Wmg[(size_t)cid * 4096 + i * 64 + (col - 128)] = f2bf(acc[r]);
    }
  }
}

// ---------- Phase 2: inter-chunk state recurrence, v-split (192 blocks) ----------
__global__ __launch_bounds__(256) void phase2_kernel(
    const unsigned short* __restrict__ kb,
    const unsigned short* __restrict__ U0g, const unsigned short* __restrict__ Wmg,
    const float* __restrict__ Gamg, unsigned short* __restrict__ P0g) {
  int blk = blockIdx.x;              // bh*4 + vc
  int vc = blk & 3, bh = blk >> 2;
  int h = bh % NHh, b = bh / NHh;
  __shared__ __align__(16) unsigned short P_bf[32][72];    // S0 slice [v][d]
  __shared__ __align__(16) unsigned short Wm_lds[64][72];  // [j][d]
  __shared__ __align__(16) unsigned short Ktmp[64][72];    // [j][d]
  __shared__ __align__(16) unsigned short KpT_lds[64][72]; // [d][j]
  __shared__ __align__(16) unsigned short U0_lds[64][40];  // [j][v32]
  __shared__ __align__(16) unsigned short UT_lds[32][72];  // [v][j]
  __shared__ float G2[64];
  int tid = threadIdx.x;
  int wave = tid >> 6, lane = tid & 63, lq = lane >> 4, lrow = lane & 15;
  int vt = wave & 1, dbase = (wave >> 1) * 2;
  f32x4 P[2] = {};
  int pj = tid >> 2, px = (tid & 3) << 4;   // Wm/K: 32B per thread
  int pv = (tid & 3) << 3;                  // U0: 16B per thread (8 shorts)
  ui4 pf_wm0, pf_wm1, pf_k0, pf_k1, pf_u0;
  float pf_g = 0.f;
  {
    size_t cid0 = (size_t)bh * NC;
    int bl0 = b * L_;
    pf_wm0 = *(const ui4*)&Wmg[cid0 * 4096 + pj * 64 + px];
    pf_wm1 = *(const ui4*)&Wmg[cid0 * 4096 + pj * 64 + px + 8];
    pf_k0  = *(const ui4*)&kb[(size_t)(bl0 + pj) * KD + h * 64 + px];
    pf_k1  = *(const ui4*)&kb[(size_t)(bl0 + pj) * KD + h * 64 + px + 8];
    pf_u0  = *(const ui4*)&U0g[cid0 * 8192 + pj * 128 + vc * 32 + pv];
    if (tid < 64) pf_g = Gamg[cid0 * 64 + tid];
  }
  for (int c = 0; c < NC; c++) {
    size_t cid = (size_t)bh * NC + c;
    #pragma unroll
    for (int di = 0; di < 2; di++)
      #pragma unroll
      for (int r = 0; r < 4; r++)
        P_bf[vt * 16 + lq * 4 + r][(dbase + di) * 16 + lrow] = f2bf(P[di][r]);
    *(ui4*)&Wm_lds[pj][px]     = pf_wm0;
    *(ui4*)&Wm_lds[pj][px + 8] = pf_wm1;
    *(ui4*)&Ktmp[pj][px]       = pf_k0;
    *(ui4*)&Ktmp[pj][px + 8]   = pf_k1;
    *(ui4*)&U0_lds[pj][pv]     = pf_u0;
    if (tid < 64) G2[tid] = pf_g;
    __syncthreads();
    float gend = __expf(G2[63]);
    {
      int v = tid >> 3, d8 = (tid & 7) << 3;
      *(ui4*)&P0g[cid * 8192 + (size_t)(vc * 32 + v) * 64 + d8] = *(const ui4*)&P_bf[v][d8];
    }
    if (c + 1 < NC) {
      size_t cid1 = cid + 1;
      int bl1 = b * L_ + ((c + 1) << 6);
      pf_wm0 = *(const ui4*)&Wmg[cid1 * 4096 + pj * 64 + px];
      pf_wm1 = *(const ui4*)&Wmg[cid1 * 4096 + pj * 64 + px + 8];
      pf_k0  = *(const ui4*)&kb[(size_t)(bl1 + pj) * KD + h * 64 + px];
      pf_k1  = *(const ui4*)&kb[(size_t)(bl1 + pj) * KD + h * 64 + px + 8];
      pf_u0  = *(const ui4*)&U0g[cid1 * 8192 + pj * 128 + vc * 32 + pv];
      if (tid < 64) pf_g = Gamg[cid1 * 64 + tid];
    }
    {
      int d = tid & 63, j0 = (tid >> 6) << 4;
      float Ge = G2[63];
      #pragma unroll
      for (int i = 0; i < 16; i++) {
        int j = j0 + i;
        KpT_lds[d][j] = f2bf(__expf(Ge - G2[j]) * bf2f(Ktmp[j][d]));
      }
    }
    #pragma unroll
    for (int vt2 = 0; vt2 < 2; vt2++) {
      f32x4 acc = {};
      #pragma unroll
      for (int ks2 = 0; ks2 < 2; ks2++) {
        bf16x8 a  = *(const bf16x8*)&Wm_lds[wave * 16 + lrow][ks2 * 32 + lq * 8];
        bf16x8 b2 = *(const bf16x8*)&P_bf[vt2 * 16 + lrow][ks2 * 32 + lq * 8];
        acc = __builtin_amdgcn_mfma_f32_16x16x32_bf16(a, b2, acc, 0, 0, 0);
      }
      u16x4 p;
      #pragma unroll
      for (int r = 0; r < 4; r++) {
        int j = wave * 16 + lq * 4 + r;
        ((unsigned short*)&p)[r] = f2bf(bf2f(U0_lds[j][vt2 * 16 + lrow]) - acc[r]);
      }
      *(u16x4*)&UT_lds[vt2 * 16 + lrow][wave * 16 + lq * 4] = p;
    }
    __syncthreads();
    #pragma unroll
    for (int di = 0; di < 2; di++) {
      f32x4 acc = P[di];
      #pragma unroll
      for (int r = 0; r < 4; r++) acc[r] *= gend;
      #pragma unroll
      for (int ks2 = 0; ks2 < 2; ks2++) {
        bf16x8 a  = *(const bf16x8*)&UT_lds[vt * 16 + lrow][ks2 * 32 + lq * 8];
        bf16x8 b2 = *(const bf16x8*)&KpT_lds[(dbase + di) * 16 + lrow][ks2 * 32 + lq * 8];
        acc = __builtin_amdgcn_mfma_f32_16x16x32_bf16(a, b2, acc, 0, 0, 0);
      }
      P[di] = acc;
    }
  }
}

// ---------- Phase 3: per-chunk output (parallel, 1536 blocks) ----------
__global__ __launch_bounds__(256) void phase3_kernel(
    const unsigned short* __restrict__ qb, const unsigned short* __restrict__ kb,
    const unsigned short* __restrict__ U0g, const unsigned short* __restrict__ Wmg,
    const unsigned short* __restrict__ P0g, const float* __restrict__ Gamg,
    unsigned short* __restrict__ o_raw) {
  int cid = blockIdx.x;
  int c = cid & (NC - 1), bh = cid >> 5;
  int h = bh % NHh, b = bh / NHh;
  int bl0 = b * L_ + (c << 6);
  __shared__ __align__(16) unsigned short Q_lds[64][72];
  __shared__ __align__(16) unsigned short K_lds[64][72];
  __shared__ __align__(16) unsigned short WM_lds[64][72];
  __shared__ __align__(16) unsigned short P0_lds[128][72];
  __shared__ __align__(16) unsigned short U0_lds[64][128];
  __shared__ __align__(16) unsigned short UT_lds[128][72];
  __shared__ float G_lds[64];
  int tid = threadIdx.x;
  int wave = tid >> 6, lane = tid & 63, lq = lane >> 4, lrow = lane & 15;
  {
    int j = tid >> 2, d0 = (tid & 3) << 4;
    const ui4* qs = (const ui4*)&qb[(size_t)(bl0 + j) * KD + h * 64 + d0];
    *(ui4*)&Q_lds[j][d0] = qs[0];  *(ui4*)&Q_lds[j][d0 + 8] = qs[1];
    const ui4* ks = (const ui4*)&kb[(size_t)(bl0 + j) * KD + h * 64 + d0];
    *(ui4*)&K_lds[j][d0] = ks[0];  *(ui4*)&K_lds[j][d0 + 8] = ks[1];
    const ui4* ws = (const ui4*)&Wmg[(size_t)cid * 4096 + j * 64 + d0];
    *(ui4*)&WM_lds[j][d0] = ws[0]; *(ui4*)&WM_lds[j][d0 + 8] = ws[1];
    int v = tid >> 1, e0 = (tid & 1) << 5;
    const ui4* ps = (const ui4*)&P0g[(size_t)cid * 8192 + v * 64 + e0];
    *(ui4*)&P0_lds[v][e0]      = ps[0]; *(ui4*)&P0_lds[v][e0 + 8]  = ps[1];
    *(ui4*)&P0_lds[v][e0 + 16] = ps[2]; *(ui4*)&P0_lds[v][e0 + 24] = ps[3];
    int e1 = tid * 32;
    const ui4* us = (const ui4*)&U0g[(size_t)cid * 8192 + e1];
    ui4* ud = (ui4*)&U0_lds[0][e1];
    ud[0] = us[0]; ud[1] = us[1]; ud[2] = us[2]; ud[3] = us[3];
    if (tid < 64) G_lds[tid] = Gamg[(size_t)cid * 64 + tid];
  }
  __syncthreads();
  #pragma unroll
  for (int nt = 0; nt < 8; nt++) {
    f32x4 acc = {};
    #pragma unroll
    for (int ks2 = 0; ks2 < 2; ks2++) {
      bf16x8 a  = *(const bf16x8*)&WM_lds[wave * 16 + lrow][ks2 * 32 + lq * 8];
      bf16x8 b2 = *(const bf16x8*)&P0_lds[nt * 16 + lrow][ks2 * 32 + lq * 8];
      acc = __builtin_amdgcn_mfma_f32_16x16x32_bf16(a, b2, acc, 0, 0, 0);
    }
    u16x4 p;
    #pragma unroll
    for (int r = 0; r < 4; r++) {
      int j = wave * 16 + lq * 4 + r;
      ((unsigned short*)&p)[r] = f2bf(bf2f(U0_lds[j][nt * 16 + lrow]) - acc[r]);
    }
    *(u16x4*)&UT_lds[nt * 16 + lrow][wave * 16 + lq * 4] = p;
  }
  __syncthreads();
  #pragma unroll
  for (int mt = 0; mt < 4; mt++) {
    f32x4 acc = {};
    #pragma unroll
    for (int ks2 = 0; ks2 < 2; ks2++) {
      bf16x8 a  = *(const bf16x8*)&Q_lds[wave * 16 + lrow][ks2 * 32 + lq * 8];
      bf16x8 b2 = *(const bf16x8*)&K_lds[mt * 16 + lrow][ks2 * 32 + lq * 8];
      acc = __builtin_amdgcn_mfma_f32_16x16x32_bf16(a, b2, acc, 0, 0, 0);
    }
    #pragma unroll
    for (int r = 0; r < 4; r++) {
      int i = wave * 16 + lq * 4 + r, j = mt * 16 + lrow;
      WM_lds[i][j] = (j <= i) ? f2bf(__expf(G_lds[i] - G_lds[j]) * acc[r]) : (unsigned short)0;
    }
  }
  __syncthreads();
  #pragma unroll
  for (int nt = 0; nt < 8; nt++) {
    f32x4 accO = {}, accS = {};
    #pragma unroll
    for (int ks2 = 0; ks2 < 2; ks2++) {
      bf16x8 aM = *(const bf16x8*)&WM_lds[wave * 16 + lrow][ks2 * 32 + lq * 8];
      bf16x8 bU = *(const bf16x8*)&UT_lds[nt * 16 + lrow][ks2 * 32 + lq * 8];
      accO = __builtin_amdgcn_mfma_f32_16x16x32_bf16(aM, bU, accO, 0, 0, 0);
      bf16x8 aQ = *(const bf16x8*)&Q_lds[wave * 16 + lrow][ks2 * 32 + lq * 8];
      bf16x8 bP = *(const bf16x8*)&P0_lds[nt * 16 + lrow][ks2 * 32 + lq * 8];
      accS = __builtin_amdgcn_mfma_f32_16x16x32_bf16(aQ, bP, accS, 0, 0, 0);
    }
    #pragma unroll
    for (int r = 0; r < 4; r++) {
      int i = wave * 16 + lq * 4 + r;
      float o = accO[r] + __expf(G_lds[i]) * accS[r];
      o_raw[(size_t)(bl0 + i) * VD + h * 128 + nt * 16 + lrow] = f2bf(o);
    }
  }
}

// ---------- rmsnorm + gnorm_w * silu(g), in-place on o_raw ----------
__global__ void norm_gate_kernel(unsigned short* __restrict__ o_raw,
                                 const unsigned short* __restrict__ g,
                                 const float* __restrict__ gnw) {
  int tid = threadIdx.x;
  int r = blockIdx.x * 16 + (tid >> 4);
  int v = (tid & 15) * 8;
  u16x8 xo = *(const u16x8*)&o_raw[(size_t)r * DVh + v];
  u16x8 xg = *(const u16x8*)&g[(size_t)r * DVh + v];
  float x[8], ss = 0.f;
  #pragma unroll
  for (int e = 0; e < 8; e++) {
    x[e] = bf2f(xo[e]);
    ss += x[e] * x[e];
  }
  #pragma unroll
  for (int off = 1; off <= 8; off <<= 1) ss += __shfl_xor(ss, off);
  float inv = rsqrtf(ss * (1.f / (float)DVh) + 1e-5f);
  f4v w0 = *(const f4v*)&gnw[v];
  f4v w1 = *(const f4v*)&gnw[v + 4];
  u16x8 o;
  #pragma unroll
  for (int e = 0; e < 8; e++) {
    float gv = bf2f(xg[e]);
    float wv = (e < 4) ? w0[e] : w1[e - 4];
    o[e] = f2bf(x[e] * inv * wv * (gv * sigmoidf_(gv)));
  }
  *(u16x8*)&o_raw[(size_t)r * DVh + v] = o;
}

// ---------- host launch ----------
extern "C" void kernel_launch(void* const* d_in, const int* in_sizes, int n_in,
                              void* d_out, int out_size, void* d_ws, size_t ws_size,
                              hipStream_t stream) {
  const void* hs      = d_in[0];
  const void* Wq      = d_in[1];
  const void* Wk      = d_in[2];
  const void* Wv      = d_in[3];
  const void* Wg      = d_in[4];
  const void* Wgk     = d_in[5];
  const void* Wb      = d_in[6];
  const void* bb      = d_in[7];
  const void* cq      = d_in[8];
  const void* ck      = d_in[9];
  const void* cv      = d_in[10];
  const void* A_log   = d_in[11];
  const void* gnorm_w = d_in[12];
  const void* Wo      = d_in[13];
  const void* dt_bias = d_in[14];

  char* wsB = (char*)d_ws;
  size_t off = 0;
  auto walloc = [&](size_t bytes) -> char* {
    char* p = wsB + off;
    off += (bytes + 1023) & ~(size_t)1023;
    return p;
  };
  int* flag = (int*)walloc(1024);
  // NOTE: WqT..WgT must stay contiguous (fused BT of [4608][1024]); all sizes
  // are multiples of 1024 so walloc adds no padding between them.
  unsigned short* WqT   = (unsigned short*)walloc((size_t)KD * H_ * 2);
  unsigned short* WkT   = (unsigned short*)walloc((size_t)KD * H_ * 2);
  unsigned short* WvT   = (unsigned short*)walloc((size_t)VD * H_ * 2);
  unsigned short* WgT   = (unsigned short*)walloc((size_t)VD * H_ * 2);
  unsigned short* WgkbT = (unsigned short*)walloc((size_t)128 * H_ * 2);
  unsigned short* WoT   = (unsigned short*)walloc((size_t)H_ * VD * 2);
  float* cqf   = (float*)walloc((size_t)KD * 4 * 4);
  float* ckf   = (float*)walloc((size_t)KD * 4 * 4);
  float* cvf   = (float*)walloc((size_t)VD * 4 * 4);
  float* bbf   = (float*)walloc(NHh * 4);
  float* A_logf= (float*)walloc(NHh * 4);
  float* dtf   = (float*)walloc(NHh * 4);
  float* gnwf  = (float*)walloc(DVh * 4);
  float* gkb   = (float*)walloc((size_t)M_ * NHh * 4);
  float* betab = (float*)walloc((size_t)M_ * NHh * 4);
  float* Gamg  = (float*)walloc((size_t)NCID * 64 * 4);
  unsigned short* c_hs  = (unsigned short*)walloc((size_t)M_ * H_ * 2);
  // qkraw/vraw/gbuf must stay contiguous (fused GEMM C routing).
  unsigned short* qkraw = (unsigned short*)walloc((size_t)M_ * 1536 * 2);
  unsigned short* vraw  = (unsigned short*)walloc((size_t)M_ * VD * 2);
  unsigned short* gbuf  = (unsigned short*)walloc((size_t)M_ * VD * 2);
  unsigned short* qb    = (unsigned short*)walloc((size_t)M_ * KD * 2);
  unsigned short* kb    = (unsigned short*)walloc((size_t)M_ * KD * 2);
  unsigned short* vb    = (unsigned short*)walloc((size_t)M_ * VD * 2);
  // overlays (safe by launch order):
  float*          logits32 = (float*)vraw;   // consumed by gkbeta BEFORE fused GEMM
  unsigned short* Wmg   = c_hs;
  unsigned short* U0g   = qkraw;
  unsigned short* o_raw = vraw;
  unsigned short* P0g   = vb;

  // 0. dtype detection + canonicalization
  detect_dtype<<<1, 256, 0, stream>>>((const unsigned short*)hs, flag);
  convert_small<<<dim3(24, 7), 256, 0, stream>>>(cq, ck, cv, bb, A_log, dt_bias, gnorm_w,
                                                 cqf, ckf, cvf, bbf, A_logf, dtf, gnwf, flag);
  transpose_conv<<<dim3(KD / 32, H_ / 32), 256, 0, stream>>>(Wq, WqT, H_, KD, flag);
  transpose_conv<<<dim3(KD / 32, H_ / 32), 256, 0, stream>>>(Wk, WkT, H_, KD, flag);
  transpose_conv<<<dim3(VD / 32, H_ / 32), 256, 0, stream>>>(Wv, WvT, H_, VD, flag);
  transpose_conv<<<dim3(VD / 32, H_ / 32), 256, 0, stream>>>(Wg, WgT, H_, VD, flag);
  transpose_conv<<<dim3(1, H_ / 32), 256, 0, stream>>>(Wgk, WgkbT, H_, NHh, flag);
  transpose_conv<<<dim3(1, H_ / 32), 256, 0, stream>>>(Wb, WgkbT + 12 * H_, H_, NHh, flag);
  transpose_conv<<<dim3(H_ / 32, VD / 32), 256, 0, stream>>>(Wo, WoT, VD, H_, flag);
  convert_hs4<<<(M_ * H_) / 1024, 256, 0, stream>>>(hs, c_hs, flag);

  // 1a. gk/beta logits first (logits32 overlays vraw; consume before fused GEMM)
  gemm_bt<<<dim3(M_ / 128, 1), 512, 0, stream>>>(c_hs, WgkbT, logits32, M_, 128, H_, 1, flag);
  gkbeta_kernel<<<(M_ * 24) / 256, 256, 0, stream>>>(logits32, bbf, A_logf, dtf, gkb, betab);
  // 1b. fused q|k|v|g projection: BT = [WqT;WkT;WvT;WgT] = [4608][1024],
  //     C routed per 128-col tile into qkraw / vraw / gbuf (mode 3)
  gemm_bt<<<dim3(M_ / 128, 4608 / 128), 512, 0, stream>>>(c_hs, WqT, qkraw, M_, 4608, H_, 3, flag);

  // 2. conv + silu (+ l2norm for q/k) — vectorized 16B/lane
  conv_qk_kernel<<<M_ / 2, 192, 0, stream>>>(qkraw, 1536, cqf, qb);
  conv_qk_kernel<<<M_ / 2, 192, 0, stream>>>(qkraw + KD, 1536, ckf, kb);
  conv_v_kernel<<<(M_ * 192) / 256, 256, 0, stream>>>(vraw, cvf, vb);

  // 3. chunked gated delta rule
  phase1_kernel<<<NCID, 256, 0, stream>>>(kb, vb, gkb, betab, U0g, Wmg, Gamg);
  phase2_kernel<<<B_ * NHh * 4, 256, 0, stream>>>(kb, U0g, Wmg, Gamg, P0g);
  phase3_kernel<<<NCID, 256, 0, stream>>>(qb, kb, U0g, Wmg, P0g, Gamg, o_raw);

  // 4. rmsnorm + swish gate (in-place on o_raw) — vectorized
  norm_gate_kernel<<<(M_ * NHh) / 16, 256, 0, stream>>>(o_raw, gbuf, gnwf);

  // 5. output projection (dtype-flag-selected store)
  gemm_bt<<<dim3(M_ / 128, H_ / 128), 512, 0, stream>>>(o_raw, WoT, d_out, M_, H_, VD, 2, flag);
}